// Round 2
// baseline (988.874 us; speedup 1.0000x reference)
//
#include <hip/hip_runtime.h>
#include <hip/hip_bf16.h>

#define LN_EPS 1e-6f

typedef __attribute__((ext_vector_type(8))) short bf16x8;
typedef __attribute__((ext_vector_type(4))) float fx4;

__device__ __forceinline__ unsigned short f2bf(float f) {
    union { __hip_bfloat16 b; unsigned short u; } cv;
    cv.b = __float2bfloat16(f);
    return cv.u;
}

// block-wide sum of (a, b) across blockDim.x (multiple of 64) threads; result broadcast
__device__ __forceinline__ float2 block_sum2(float a, float b) {
    __shared__ float sa[8], sb[8];
    #pragma unroll
    for (int off = 1; off < 64; off <<= 1) {
        a += __shfl_xor(a, off);
        b += __shfl_xor(b, off);
    }
    int w = threadIdx.x >> 6;
    if ((threadIdx.x & 63) == 0) { sa[w] = a; sb[w] = b; }
    __syncthreads();
    int nw = blockDim.x >> 6;
    float ra = 0.f, rb = 0.f;
    for (int i = 0; i < nw; ++i) { ra += sa[i]; rb += sb[i]; }
    __syncthreads();
    return make_float2(ra, rb);
}

// ---------- pad dtype detector: u8 bool vs int32 ----------
__global__ void k_pad(const unsigned char* __restrict__ p, float* __restrict__ padf) {
    __shared__ int cnt;
    int t = threadIdx.x;                  // 512 threads
    if (t == 0) cnt = 0;
    __syncthreads();
    if (p[t]) atomicAdd(&cnt, 1);
    __syncthreads();
    float v;
    if (cnt > 256) v = p[t] ? 1.f : 0.f;                       // u8 bools
    else           v = ((const int*)p)[t] ? 1.f : 0.f;          // int32 (or f32 bits) per elem
    padf[t] = v;
}

// ---------- conv0 (3x3, 4->32) + bias + LN(32) + ReLU -> bf16 ----------
__global__ __launch_bounds__(256) void k_conv0(
    const float* __restrict__ x, const float* __restrict__ w,
    const float* __restrict__ bias, const float* __restrict__ lns, const float* __restrict__ lnb,
    unsigned short* __restrict__ a0)
{
    int pid = blockIdx.x * 256 + threadIdx.x;   // 512*7056 exactly
    int img = pid / 7056;
    int p = pid - img * 7056;
    int py = p / 84;
    int px = p - py * 84;

    float acc[32];
    #pragma unroll
    for (int c = 0; c < 32; ++c) acc[c] = bias[c];

    #pragma unroll
    for (int dy = 0; dy < 3; ++dy) {
        int yy = py + dy - 1;
        if (yy < 0 || yy >= 84) continue;
        #pragma unroll
        for (int dx = 0; dx < 3; ++dx) {
            int xx = px + dx - 1;
            if (xx < 0 || xx >= 84) continue;
            float4 v = *reinterpret_cast<const float4*>(x + ((size_t)img * 7056 + yy * 84 + xx) * 4);
            const float* wt = w + (dy * 3 + dx) * 128;   // (3,3,4,32)
            #pragma unroll
            for (int ci = 0; ci < 4; ++ci) {
                float xv = (&v.x)[ci];
                #pragma unroll
                for (int c = 0; c < 32; ++c)
                    acc[c] = fmaf(xv, wt[ci * 32 + c], acc[c]);
            }
        }
    }
    float m = 0.f;
    #pragma unroll
    for (int c = 0; c < 32; ++c) m += acc[c];
    m *= (1.f / 32.f);
    float var = 0.f;
    #pragma unroll
    for (int c = 0; c < 32; ++c) { float d = acc[c] - m; var = fmaf(d, d, var); }
    var *= (1.f / 32.f);
    float inv = rsqrtf(var + LN_EPS);
    unsigned short ob[32];
    #pragma unroll
    for (int c = 0; c < 32; ++c) {
        float o = (acc[c] - m) * inv * lns[c] + lnb[c];
        ob[c] = f2bf(fmaxf(o, 0.f));
    }
    uint4* dst = reinterpret_cast<uint4*>(a0 + (size_t)pid * 32);
    #pragma unroll
    for (int g = 0; g < 4; ++g) {
        uint4 pk;
        pk.x = (unsigned)ob[g * 8 + 0] | ((unsigned)ob[g * 8 + 1] << 16);
        pk.y = (unsigned)ob[g * 8 + 2] | ((unsigned)ob[g * 8 + 3] << 16);
        pk.z = (unsigned)ob[g * 8 + 4] | ((unsigned)ob[g * 8 + 5] << 16);
        pk.w = (unsigned)ob[g * 8 + 6] | ((unsigned)ob[g * 8 + 7] << 16);
        dst[g] = pk;
    }
}

// ---------- conv1 weight repack: (3,3,32,64) f32 -> wtb[tap][co][kg][j] bf16 ----------
__global__ void k_wprep(const float* __restrict__ w, unsigned short* __restrict__ wtb) {
    int idx = blockIdx.x * 256 + threadIdx.x;   // 18432 exactly
    int j  = idx & 7;
    int kg = (idx >> 3) & 3;
    int co = (idx >> 5) & 63;
    int tp = idx >> 11;
    float v = w[((size_t)tp * 32 + kg * 8 + j) * 64 + co];
    wtb[idx] = f2bf(v);
}

// ---------- conv1 (3x3, 32->64) LDS-staged implicit GEMM + bias + LN(64) + ReLU + mean-pool ----------
// Block: one image x 3 output rows (252 px -> 256 = 4 waves x 4 m-tiles x 16 px).
// LDS A-tile: channel-plane-major At[kg][5 rows][86 cols][8 ch] bf16, zero-padded halo.
__global__ __launch_bounds__(256, 4) void k_conv1(
    const unsigned short* __restrict__ a0, const unsigned short* __restrict__ wtb,
    const float* __restrict__ bias, const float* __restrict__ lns, const float* __restrict__ lnb,
    float* __restrict__ pooled)
{
    __shared__ __align__(16) unsigned short At[4][5][86][8];   // 27520 B
    __shared__ float pool_s[64];
    const int tid = threadIdx.x;
    const int img = blockIdx.x / 28;
    const int rg  = blockIdx.x - img * 28;
    const int y0  = rg * 3;

    if (tid < 64) pool_s[tid] = 0.f;
    // zero-pad columns 0 and 85 (x halo)
    if (tid >= 64 && tid < 104) {
        int z = tid - 64;                   // 0..39
        int zk = z / 10, rem = z - zk * 10, zr = rem >> 1, side = rem & 1;
        *reinterpret_cast<uint4*>(&At[zk][zr][side ? 85 : 0][0]) = (uint4){0, 0, 0, 0};
    }
    // main staging: 5 rows x 84 px x 4 kg = 1680 x 16B, fully coalesced
    {
        const size_t ibase = (size_t)img * 7056 * 32;
        #pragma unroll
        for (int it = 0; it < 7; ++it) {
            int i = tid + it * 256;
            if (i < 1680) {
                int skg = i & 3, t2 = i >> 2;
                int r = t2 / 84, px = t2 - r * 84;
                int gy = y0 - 1 + r;
                uint4 v = (uint4){0, 0, 0, 0};
                if (gy >= 0 && gy < 84)
                    v = *reinterpret_cast<const uint4*>(a0 + ibase + (size_t)(gy * 84 + px) * 32 + skg * 8);
                *reinterpret_cast<uint4*>(&At[skg][r][px + 1][0]) = v;
            }
        }
    }
    __syncthreads();

    const int lane = tid & 63;
    const int wv = tid >> 6;
    const int lo = lane & 15;     // A-row (pixel) / B-col (channel)
    const int kg = lane >> 4;     // k-group

    // per-m A base offsets (ushort units) into At
    int abase[4];
    #pragma unroll
    for (int m = 0; m < 4; ++m) {
        int pl = wv * 64 + m * 16 + lo;
        if (pl > 251) pl = 251;
        int rl = pl / 84;
        int c = pl - rl * 84;
        abase[m] = ((kg * 5 + rl) * 86 + c) * 8;
    }

    fx4 acc[4][4];
    #pragma unroll
    for (int m = 0; m < 4; ++m)
        #pragma unroll
        for (int n = 0; n < 4; ++n) acc[m][n] = (fx4){0.f, 0.f, 0.f, 0.f};

    const unsigned short* Abase = &At[0][0][0][0];
    #pragma unroll
    for (int dy = 0; dy < 3; ++dy) {
        #pragma unroll
        for (int dx = 0; dx < 3; ++dx) {
            const int t = dy * 3 + dx;
            bf16x8 Bf[4];
            #pragma unroll
            for (int n = 0; n < 4; ++n)
                Bf[n] = *reinterpret_cast<const bf16x8*>(
                    wtb + (size_t)((t * 64 + n * 16 + lo) * 4 + kg) * 8);
            #pragma unroll
            for (int m = 0; m < 4; ++m) {
                bf16x8 Af = *reinterpret_cast<const bf16x8*>(Abase + abase[m] + (dy * 86 + dx) * 8);
                #pragma unroll
                for (int n = 0; n < 4; ++n)
                    acc[m][n] = __builtin_amdgcn_mfma_f32_16x16x32_bf16(Af, Bf[n], acc[m][n], 0, 0, 0);
            }
        }
    }

    // epilogue: bias + LN(64) + ReLU + pool.  D: pixel = wv*64 + m*16 + kg*4 + r, channel = n*16 + lo
    float bs[4], ss[4], bb[4];
    #pragma unroll
    for (int n = 0; n < 4; ++n) {
        int c = n * 16 + lo;
        bs[n] = bias[c]; ss[n] = lns[c]; bb[n] = lnb[c];
    }
    float pv[4] = {0.f, 0.f, 0.f, 0.f};
    #pragma unroll
    for (int m = 0; m < 4; ++m) {
        #pragma unroll
        for (int r = 0; r < 4; ++r) {
            float v0 = acc[m][0][r] + bs[0], v1 = acc[m][1][r] + bs[1];
            float v2 = acc[m][2][r] + bs[2], v3 = acc[m][3][r] + bs[3];
            float s = v0 + v1 + v2 + v3;
            float q = v0 * v0 + v1 * v1 + v2 * v2 + v3 * v3;
            #pragma unroll
            for (int off = 1; off < 16; off <<= 1) {
                s += __shfl_xor(s, off);
                q += __shfl_xor(q, off);
            }
            float mn = s * (1.f / 64.f);
            float var = q * (1.f / 64.f) - mn * mn;
            float inv = rsqrtf(var + LN_EPS);
            int pix = wv * 64 + m * 16 + kg * 4 + r;
            float valid = (pix < 252) ? 1.f : 0.f;
            pv[0] += fmaxf((v0 - mn) * inv * ss[0] + bb[0], 0.f) * valid;
            pv[1] += fmaxf((v1 - mn) * inv * ss[1] + bb[1], 0.f) * valid;
            pv[2] += fmaxf((v2 - mn) * inv * ss[2] + bb[2], 0.f) * valid;
            pv[3] += fmaxf((v3 - mn) * inv * ss[3] + bb[3], 0.f) * valid;
        }
    }
    #pragma unroll
    for (int n = 0; n < 4; ++n) {
        float v = pv[n];
        v += __shfl_xor(v, 16);
        v += __shfl_xor(v, 32);
        if (lane < 16) atomicAdd(&pool_s[n * 16 + lane], v);
    }
    __syncthreads();
    if (tid < 64) atomicAdd(&pooled[img * 64 + tid], pool_s[tid]);
}

// ---------- pooled mean -> proj(64->256) + bias + LN ----------
__global__ __launch_bounds__(256) void k_pool_proj(
    const float* __restrict__ pooled, const float* __restrict__ W,
    const float* __restrict__ pb, const float* __restrict__ lns, const float* __restrict__ lnb,
    float* __restrict__ h)
{
    __shared__ float sm[64];
    int row = blockIdx.x, t = threadIdx.x;
    if (t < 64) sm[t] = pooled[row * 64 + t] * (1.f / 7056.f);
    __syncthreads();
    float acc = pb[t];
    #pragma unroll 8
    for (int k = 0; k < 64; ++k) acc = fmaf(sm[k], W[k * 256 + t], acc);
    float2 sq = block_sum2(acc, acc * acc);
    float m = sq.x * (1.f / 256.f);
    float var = sq.y * (1.f / 256.f) - m * m;
    h[row * 256 + t] = (acc - m) * rsqrtf(var + LN_EPS) * lns[t] + lnb[t];
}

// ---------- qkv projection + RoPE -> q,k,v in (b, nh, s, hd) ----------
__global__ __launch_bounds__(256) void k_qkv_rope(
    const float* __restrict__ h, const float* __restrict__ W, const float* __restrict__ bvec,
    float* __restrict__ qb, float* __restrict__ kb, float* __restrict__ vb)
{
    __shared__ float hr[256];
    __shared__ float qkv[768];
    int row = blockIdx.x, t = threadIdx.x;
    hr[t] = h[row * 256 + t];
    __syncthreads();
    #pragma unroll
    for (int m = 0; m < 3; ++m) {
        int col = m * 256 + t;
        float acc = bvec[col];
        #pragma unroll 8
        for (int k = 0; k < 256; ++k) acc = fmaf(hr[k], W[k * 768 + col], acc);
        qkv[col] = acc;
    }
    __syncthreads();
    int b = row >> 5, s = row & 31;
    int hd_i = t >> 6, d = t & 63;
    size_t dst = ((size_t)(b * 4 + hd_i) * 32 + s) * 64 + d;
    int j = d >> 1;
    // inv_freq = 10000^(-2j/64) = 2^(-j * (2/64) * log2(10000))
    float freq = exp2f(-(float)j * 0.41524101186f);
    float ang = (float)s * freq;
    float sn, cs;
    sincosf(ang, &sn, &cs);
    {
        float xe = qkv[t & ~1], xo = qkv[t | 1];
        qb[dst] = (d & 1) ? (xo * cs + xe * sn) : (xe * cs - xo * sn);
    }
    {
        float xe = qkv[256 + (t & ~1)], xo = qkv[256 + (t | 1)];
        kb[dst] = (d & 1) ? (xo * cs + xe * sn) : (xe * cs - xo * sn);
    }
    vb[dst] = qkv[512 + t];
}

// ---------- attention per (b, head): softmax(mask(QK^T*scale)) @ V ----------
__global__ __launch_bounds__(256) void k_attn(
    const float* __restrict__ qb, const float* __restrict__ kb, const float* __restrict__ vb,
    const float* __restrict__ padf, float* __restrict__ y)
{
    __shared__ float Q[32][65], K[32][65], V[32][65], P[32][33];
    int bh = blockIdx.x;              // b*4 + h
    int b = bh >> 2, hh = bh & 3;
    int t = threadIdx.x;
    #pragma unroll
    for (int i = 0; i < 8; ++i) {
        int idx = t + i * 256;        // 0..2047
        int r = idx >> 6, d = idx & 63;
        Q[r][d] = qb[(size_t)bh * 2048 + idx];
        K[r][d] = kb[(size_t)bh * 2048 + idx];
        V[r][d] = vb[(size_t)bh * 2048 + idx];
    }
    __syncthreads();
    int r = t >> 3, k8 = t & 7;
    #pragma unroll
    for (int i = 0; i < 4; ++i) {
        int kk = k8 + i * 8;
        float acc = 0.f;
        #pragma unroll
        for (int d = 0; d < 64; ++d) acc = fmaf(Q[r][d], K[kk][d], acc);
        acc *= 0.125f;
        bool ok = (kk <= r) && (padf[b * 32 + kk] != 0.f);
        P[r][kk] = ok ? acc : -1e9f;
    }
    __syncthreads();
    if (t < 32) {
        float mx = -1e30f;
        #pragma unroll
        for (int kk = 0; kk < 32; ++kk) mx = fmaxf(mx, P[t][kk]);
        float sum = 0.f, e[32];
        #pragma unroll
        for (int kk = 0; kk < 32; ++kk) { e[kk] = __expf(P[t][kk] - mx); sum += e[kk]; }
        float inv = 1.f / sum;
        #pragma unroll
        for (int kk = 0; kk < 32; ++kk) P[t][kk] = e[kk] * inv;
    }
    __syncthreads();
    int d0 = (t & 7) * 8;
    float o[8] = {0.f, 0.f, 0.f, 0.f, 0.f, 0.f, 0.f, 0.f};
    for (int kk = 0; kk < 32; ++kk) {
        float a = P[r][kk];
        #pragma unroll
        for (int jj = 0; jj < 8; ++jj) o[jj] = fmaf(a, V[kk][d0 + jj], o[jj]);
    }
    float* dst = y + ((size_t)(b * 32 + r) * 256 + hh * 64 + d0);
    #pragma unroll
    for (int jj = 0; jj < 8; ++jj) dst[jj] = o[jj];
}

// ---------- attn out-proj + pad mask + LN + residual (in-place h) ----------
__global__ __launch_bounds__(256) void k_attn_out(
    const float* __restrict__ y, const float* __restrict__ W, const float* __restrict__ bvec,
    const float* __restrict__ padf, const float* __restrict__ lns, const float* __restrict__ lnb,
    float* __restrict__ h)
{
    __shared__ float yr[256];
    int row = blockIdx.x, t = threadIdx.x;
    yr[t] = y[row * 256 + t];
    __syncthreads();
    float acc = bvec[t];
    #pragma unroll 8
    for (int k = 0; k < 256; ++k) acc = fmaf(yr[k], W[k * 256 + t], acc);
    acc *= padf[row];
    float2 sq = block_sum2(acc, acc * acc);
    float m = sq.x * (1.f / 256.f);
    float var = sq.y * (1.f / 256.f) - m * m;
    float res = h[row * 256 + t];
    h[row * 256 + t] = (acc - m) * rsqrtf(var + LN_EPS) * lns[t] + lnb[t] + res;
}

// ---------- MLP up (256->512) + ReLU ----------
__global__ __launch_bounds__(256) void k_mlp_up(
    const float* __restrict__ h, const float* __restrict__ W, float* __restrict__ u)
{
    __shared__ float hr[256];
    int row = blockIdx.x, t = threadIdx.x;
    hr[t] = h[row * 256 + t];
    __syncthreads();
    float a0 = 0.f, a1 = 0.f;
    #pragma unroll 8
    for (int k = 0; k < 256; ++k) {
        float hk = hr[k];
        a0 = fmaf(hk, W[k * 512 + t], a0);
        a1 = fmaf(hk, W[k * 512 + 256 + t], a1);
    }
    u[row * 512 + t] = fmaxf(a0, 0.f);
    u[row * 512 + 256 + t] = fmaxf(a1, 0.f);
}

// ---------- MLP down (512->256) + LN + residual (in-place h) ----------
__global__ __launch_bounds__(256) void k_mlp_down(
    const float* __restrict__ u, const float* __restrict__ W,
    const float* __restrict__ lns, const float* __restrict__ lnb, float* __restrict__ h)
{
    __shared__ float ur[512];
    int row = blockIdx.x, t = threadIdx.x;
    ur[t] = u[row * 512 + t];
    ur[t + 256] = u[row * 512 + 256 + t];
    __syncthreads();
    float acc = 0.f;
    #pragma unroll 8
    for (int k = 0; k < 512; ++k) acc = fmaf(ur[k], W[k * 256 + t], acc);
    float2 sq = block_sum2(acc, acc * acc);
    float m = sq.x * (1.f / 256.f);
    float var = sq.y * (1.f / 256.f) - m * m;
    float res = h[row * 256 + t];
    h[row * 256 + t] = (acc - m) * rsqrtf(var + LN_EPS) * lns[t] + lnb[t] + res;
}

// ---------- head (256->18) ----------
__global__ __launch_bounds__(256) void k_head(
    const float* __restrict__ h, const float* __restrict__ W, const float* __restrict__ b,
    float* __restrict__ out)
{
    __shared__ float hr[256];
    int row = blockIdx.x, t = threadIdx.x;
    hr[t] = h[row * 256 + t];
    __syncthreads();
    if (t < 18) {
        float acc = b[t];
        #pragma unroll 8
        for (int k = 0; k < 256; ++k) acc = fmaf(hr[k], W[k * 18 + t], acc);
        out[row * 18 + t] = acc;
    }
}

extern "C" void kernel_launch(void* const* d_in, const int* in_sizes, int n_in,
                              void* d_out, int out_size, void* d_ws, size_t ws_size,
                              hipStream_t stream)
{
    (void)in_sizes; (void)n_in; (void)out_size; (void)ws_size;
    const float* x   = (const float*)d_in[0];
    const unsigned char* pad = (const unsigned char*)d_in[1];
    const float* c0w = (const float*)d_in[2];
    const float* c0b = (const float*)d_in[3];
    const float* l0s = (const float*)d_in[4];
    const float* l0b = (const float*)d_in[5];
    const float* c1w = (const float*)d_in[6];
    const float* c1b = (const float*)d_in[7];
    const float* l1s = (const float*)d_in[8];
    const float* l1b = (const float*)d_in[9];
    const float* pw  = (const float*)d_in[10];
    const float* pb  = (const float*)d_in[11];
    const float* lps = (const float*)d_in[12];
    const float* lpb = (const float*)d_in[13];
    const float* qkvw = (const float*)d_in[14];
    const float* qkvb = (const float*)d_in[15];
    const float* ow  = (const float*)d_in[16];
    const float* obv = (const float*)d_in[17];
    const float* las = (const float*)d_in[18];
    const float* lab = (const float*)d_in[19];
    const float* upw = (const float*)d_in[20];
    const float* dww = (const float*)d_in[21];
    const float* lms = (const float*)d_in[22];
    const float* lmb = (const float*)d_in[23];
    const float* hw  = (const float*)d_in[24];
    const float* hb  = (const float*)d_in[25];
    float* out = (float*)d_out;

    char* ws = (char*)d_ws;
    size_t off = 0;
    auto alloc = [&](size_t bytes) -> void* {
        void* p = ws + off;
        off = (off + bytes + 255) & ~(size_t)255;
        return p;
    };
    unsigned short* a0  = (unsigned short*)alloc((size_t)512 * 7056 * 32 * 2);
    unsigned short* wtb = (unsigned short*)alloc(18432 * 2);
    float* pooled = (float*)alloc(512 * 64 * 4);
    float* padf   = (float*)alloc(512 * 4);
    float* h      = (float*)alloc(512 * 256 * 4);
    float* qb     = (float*)alloc(512 * 256 * 4);
    float* kb     = (float*)alloc(512 * 256 * 4);
    float* vb     = (float*)alloc(512 * 256 * 4);
    float* yb     = (float*)alloc(512 * 256 * 4);
    float* ub     = (float*)alloc(512 * 512 * 4);

    hipMemsetAsync(pooled, 0, 512 * 64 * 4, stream);
    k_pad<<<1, 512, 0, stream>>>(pad, padf);
    k_conv0<<<14112, 256, 0, stream>>>(x, c0w, c0b, l0s, l0b, a0);
    k_wprep<<<72, 256, 0, stream>>>(c1w, wtb);
    k_conv1<<<14336, 256, 0, stream>>>(a0, wtb, c1b, l1s, l1b, pooled);
    k_pool_proj<<<512, 256, 0, stream>>>(pooled, pw, pb, lps, lpb, h);
    for (int i = 0; i < 2; ++i) {
        k_qkv_rope<<<512, 256, 0, stream>>>(h, qkvw + (size_t)i * 256 * 768, qkvb + i * 768, qb, kb, vb);
        k_attn<<<64, 256, 0, stream>>>(qb, kb, vb, padf, yb);
        k_attn_out<<<512, 256, 0, stream>>>(yb, ow + (size_t)i * 256 * 256, obv + i * 256,
                                            padf, las + i * 256, lab + i * 256, h);
        k_mlp_up<<<512, 256, 0, stream>>>(h, upw + (size_t)i * 256 * 512, ub);
        k_mlp_down<<<512, 256, 0, stream>>>(ub, dww + (size_t)i * 512 * 256,
                                            lms + i * 256, lmb + i * 256, h);
    }
    k_head<<<512, 256, 0, stream>>>(h, hw, hb, out);
}

// Round 3
// 653.929 us; speedup vs baseline: 1.5122x; 1.5122x over previous
//
#include <hip/hip_runtime.h>
#include <hip/hip_bf16.h>

#define LN_EPS 1e-6f

typedef __attribute__((ext_vector_type(8))) short bf16x8;
typedef __attribute__((ext_vector_type(4))) float fx4;

__device__ __forceinline__ unsigned short f2bf(float f) {
    union { __hip_bfloat16 b; unsigned short u; } cv;
    cv.b = __float2bfloat16(f);
    return cv.u;
}

// block-wide sum of (a, b) across blockDim.x (multiple of 64) threads; result broadcast
__device__ __forceinline__ float2 block_sum2(float a, float b) {
    __shared__ float sa[8], sb[8];
    #pragma unroll
    for (int off = 1; off < 64; off <<= 1) {
        a += __shfl_xor(a, off);
        b += __shfl_xor(b, off);
    }
    int w = threadIdx.x >> 6;
    if ((threadIdx.x & 63) == 0) { sa[w] = a; sb[w] = b; }
    __syncthreads();
    int nw = blockDim.x >> 6;
    float ra = 0.f, rb = 0.f;
    for (int i = 0; i < nw; ++i) { ra += sa[i]; rb += sb[i]; }
    __syncthreads();
    return make_float2(ra, rb);
}

// ---------- pad dtype detector: u8 bool vs int32 ----------
__global__ void k_pad(const unsigned char* __restrict__ p, float* __restrict__ padf) {
    __shared__ int cnt;
    int t = threadIdx.x;                  // 512 threads
    if (t == 0) cnt = 0;
    __syncthreads();
    if (p[t]) atomicAdd(&cnt, 1);
    __syncthreads();
    float v;
    if (cnt > 256) v = p[t] ? 1.f : 0.f;                       // u8 bools
    else           v = ((const int*)p)[t] ? 1.f : 0.f;          // int32 (or f32 bits) per elem
    padf[t] = v;
}

// ---------- conv0 (3x3, 4->32) + bias + LN(32) + ReLU -> bf16 ----------
__global__ __launch_bounds__(256) void k_conv0(
    const float* __restrict__ x, const float* __restrict__ w,
    const float* __restrict__ bias, const float* __restrict__ lns, const float* __restrict__ lnb,
    unsigned short* __restrict__ a0)
{
    int pid = blockIdx.x * 256 + threadIdx.x;   // 512*7056 exactly
    int img = pid / 7056;
    int p = pid - img * 7056;
    int py = p / 84;
    int px = p - py * 84;

    float acc[32];
    #pragma unroll
    for (int c = 0; c < 32; ++c) acc[c] = bias[c];

    #pragma unroll
    for (int dy = 0; dy < 3; ++dy) {
        int yy = py + dy - 1;
        if (yy < 0 || yy >= 84) continue;
        #pragma unroll
        for (int dx = 0; dx < 3; ++dx) {
            int xx = px + dx - 1;
            if (xx < 0 || xx >= 84) continue;
            float4 v = *reinterpret_cast<const float4*>(x + ((size_t)img * 7056 + yy * 84 + xx) * 4);
            const float* wt = w + (dy * 3 + dx) * 128;   // (3,3,4,32)
            #pragma unroll
            for (int ci = 0; ci < 4; ++ci) {
                float xv = (&v.x)[ci];
                #pragma unroll
                for (int c = 0; c < 32; ++c)
                    acc[c] = fmaf(xv, wt[ci * 32 + c], acc[c]);
            }
        }
    }
    float m = 0.f;
    #pragma unroll
    for (int c = 0; c < 32; ++c) m += acc[c];
    m *= (1.f / 32.f);
    float var = 0.f;
    #pragma unroll
    for (int c = 0; c < 32; ++c) { float d = acc[c] - m; var = fmaf(d, d, var); }
    var *= (1.f / 32.f);
    float inv = rsqrtf(var + LN_EPS);
    unsigned short ob[32];
    #pragma unroll
    for (int c = 0; c < 32; ++c) {
        float o = (acc[c] - m) * inv * lns[c] + lnb[c];
        ob[c] = f2bf(fmaxf(o, 0.f));
    }
    uint4* dst = reinterpret_cast<uint4*>(a0 + (size_t)pid * 32);
    #pragma unroll
    for (int g = 0; g < 4; ++g) {
        uint4 pk;
        pk.x = (unsigned)ob[g * 8 + 0] | ((unsigned)ob[g * 8 + 1] << 16);
        pk.y = (unsigned)ob[g * 8 + 2] | ((unsigned)ob[g * 8 + 3] << 16);
        pk.z = (unsigned)ob[g * 8 + 4] | ((unsigned)ob[g * 8 + 5] << 16);
        pk.w = (unsigned)ob[g * 8 + 6] | ((unsigned)ob[g * 8 + 7] << 16);
        dst[g] = pk;
    }
}

// ---------- conv1 weight repack: (3,3,32,64) f32 -> wtb[tap][co][kg][j] bf16 ----------
__global__ void k_wprep(const float* __restrict__ w, unsigned short* __restrict__ wtb) {
    int idx = blockIdx.x * 256 + threadIdx.x;   // 18432 exactly
    int j  = idx & 7;
    int kg = (idx >> 3) & 3;
    int co = (idx >> 5) & 63;
    int tp = idx >> 11;
    float v = w[((size_t)tp * 32 + kg * 8 + j) * 64 + co];
    wtb[idx] = f2bf(v);
}

// ---------- conv1 (3x3, 32->64) LDS-staged implicit GEMM + bias + LN(64) + ReLU + mean-pool ----------
// Block: one image x 3 output rows (252 px -> 256 = 4 waves x 4 m-tiles x 16 px).
// LDS A-tile: channel-plane-major At[kg][5 rows][86 cols][8 ch] bf16, zero-padded halo.
// launch_bounds(256,2): ~256 unified VGPR+AGPR per wave -> no scratch spills (R2 lesson:
// (256,4) capped at 128 and spilled ~1.1 GB of scratch traffic per dispatch).
__global__ __launch_bounds__(256, 2) void k_conv1(
    const unsigned short* __restrict__ a0, const unsigned short* __restrict__ wtb,
    const float* __restrict__ bias, const float* __restrict__ lns, const float* __restrict__ lnb,
    float* __restrict__ pooled)
{
    __shared__ __align__(16) unsigned short At[4][5][86][8];   // 27520 B
    __shared__ float pool_w[4][64];
    const int tid = threadIdx.x;
    const int img = blockIdx.x / 28;
    const int rg  = blockIdx.x - img * 28;
    const int y0  = rg * 3;

    // zero-pad columns 0 and 85 (x halo)
    if (tid >= 64 && tid < 104) {
        int z = tid - 64;                   // 0..39
        int zk = z / 10, rem = z - zk * 10, zr = rem >> 1, side = rem & 1;
        *reinterpret_cast<uint4*>(&At[zk][zr][side ? 85 : 0][0]) = (uint4){0, 0, 0, 0};
    }
    // main staging: 5 rows x 84 px x 4 kg = 1680 x 16B, fully coalesced
    {
        const size_t ibase = (size_t)img * 7056 * 32;
        #pragma unroll
        for (int it = 0; it < 7; ++it) {
            int i = tid + it * 256;
            if (i < 1680) {
                int skg = i & 3, t2 = i >> 2;
                int r = t2 / 84, px = t2 - r * 84;
                int gy = y0 - 1 + r;
                uint4 v = (uint4){0, 0, 0, 0};
                if (gy >= 0 && gy < 84)
                    v = *reinterpret_cast<const uint4*>(a0 + ibase + (size_t)(gy * 84 + px) * 32 + skg * 8);
                *reinterpret_cast<uint4*>(&At[skg][r][px + 1][0]) = v;
            }
        }
    }
    __syncthreads();

    const int lane = tid & 63;
    const int wv = tid >> 6;
    const int lo = lane & 15;     // A-row (pixel) / B-col (channel)
    const int kg = lane >> 4;     // k-group

    // per-m A base offsets (ushort units) into At
    int abase[4];
    #pragma unroll
    for (int m = 0; m < 4; ++m) {
        int pl = wv * 64 + m * 16 + lo;
        if (pl > 251) pl = 251;
        int rl = pl / 84;
        int c = pl - rl * 84;
        abase[m] = ((kg * 5 + rl) * 86 + c) * 8;
    }

    fx4 acc[4][4];
    #pragma unroll
    for (int m = 0; m < 4; ++m)
        #pragma unroll
        for (int n = 0; n < 4; ++n) acc[m][n] = (fx4){0.f, 0.f, 0.f, 0.f};

    const unsigned short* Abase = &At[0][0][0][0];
    #pragma unroll
    for (int dy = 0; dy < 3; ++dy) {
        #pragma unroll
        for (int dx = 0; dx < 3; ++dx) {
            const int t = dy * 3 + dx;
            bf16x8 Bf[4];
            #pragma unroll
            for (int n = 0; n < 4; ++n)
                Bf[n] = *reinterpret_cast<const bf16x8*>(
                    wtb + (size_t)((t * 64 + n * 16 + lo) * 4 + kg) * 8);
            #pragma unroll
            for (int m = 0; m < 4; ++m) {
                bf16x8 Af = *reinterpret_cast<const bf16x8*>(Abase + abase[m] + (dy * 86 + dx) * 8);
                #pragma unroll
                for (int n = 0; n < 4; ++n)
                    acc[m][n] = __builtin_amdgcn_mfma_f32_16x16x32_bf16(Af, Bf[n], acc[m][n], 0, 0, 0);
            }
        }
    }

    // epilogue: bias + LN(64) + ReLU + pool.  D: pixel = wv*64 + m*16 + kg*4 + r, channel = n*16 + lo
    float bs[4], ss[4], bb[4];
    #pragma unroll
    for (int n = 0; n < 4; ++n) {
        int c = n * 16 + lo;
        bs[n] = bias[c]; ss[n] = lns[c]; bb[n] = lnb[c];
    }
    float pv[4] = {0.f, 0.f, 0.f, 0.f};
    #pragma unroll
    for (int m = 0; m < 4; ++m) {
        #pragma unroll
        for (int r = 0; r < 4; ++r) {
            float v0 = acc[m][0][r] + bs[0], v1 = acc[m][1][r] + bs[1];
            float v2 = acc[m][2][r] + bs[2], v3 = acc[m][3][r] + bs[3];
            float s = v0 + v1 + v2 + v3;
            float q = v0 * v0 + v1 * v1 + v2 * v2 + v3 * v3;
            #pragma unroll
            for (int off = 1; off < 16; off <<= 1) {
                s += __shfl_xor(s, off);
                q += __shfl_xor(q, off);
            }
            float mn = s * (1.f / 64.f);
            float var = q * (1.f / 64.f) - mn * mn;
            float inv = rsqrtf(var + LN_EPS);
            int pix = wv * 64 + m * 16 + kg * 4 + r;
            float valid = (pix < 252) ? 1.f : 0.f;
            pv[0] += fmaxf((v0 - mn) * inv * ss[0] + bb[0], 0.f) * valid;
            pv[1] += fmaxf((v1 - mn) * inv * ss[1] + bb[1], 0.f) * valid;
            pv[2] += fmaxf((v2 - mn) * inv * ss[2] + bb[2], 0.f) * valid;
            pv[3] += fmaxf((v3 - mn) * inv * ss[3] + bb[3], 0.f) * valid;
        }
    }
    // per-wave pool slice (no LDS atomics — R2's 8.3M bank-conflict source)
    #pragma unroll
    for (int n = 0; n < 4; ++n) {
        float v = pv[n];
        v += __shfl_xor(v, 16);
        v += __shfl_xor(v, 32);
        if (lane < 16) pool_w[wv][n * 16 + lane] = v;
    }
    __syncthreads();
    if (tid < 64) {
        float s = pool_w[0][tid] + pool_w[1][tid] + pool_w[2][tid] + pool_w[3][tid];
        atomicAdd(&pooled[img * 64 + tid], s);
    }
}

// ---------- pooled mean -> proj(64->256) + bias + LN ----------
__global__ __launch_bounds__(256) void k_pool_proj(
    const float* __restrict__ pooled, const float* __restrict__ W,
    const float* __restrict__ pb, const float* __restrict__ lns, const float* __restrict__ lnb,
    float* __restrict__ h)
{
    __shared__ float sm[64];
    int row = blockIdx.x, t = threadIdx.x;
    if (t < 64) sm[t] = pooled[row * 64 + t] * (1.f / 7056.f);
    __syncthreads();
    float acc = pb[t];
    #pragma unroll 8
    for (int k = 0; k < 64; ++k) acc = fmaf(sm[k], W[k * 256 + t], acc);
    float2 sq = block_sum2(acc, acc * acc);
    float m = sq.x * (1.f / 256.f);
    float var = sq.y * (1.f / 256.f) - m * m;
    h[row * 256 + t] = (acc - m) * rsqrtf(var + LN_EPS) * lns[t] + lnb[t];
}

// ---------- qkv projection + RoPE -> q,k,v in (b, nh, s, hd) ----------
__global__ __launch_bounds__(256) void k_qkv_rope(
    const float* __restrict__ h, const float* __restrict__ W, const float* __restrict__ bvec,
    float* __restrict__ qb, float* __restrict__ kb, float* __restrict__ vb)
{
    __shared__ float hr[256];
    __shared__ float qkv[768];
    int row = blockIdx.x, t = threadIdx.x;
    hr[t] = h[row * 256 + t];
    __syncthreads();
    #pragma unroll
    for (int m = 0; m < 3; ++m) {
        int col = m * 256 + t;
        float acc = bvec[col];
        #pragma unroll 8
        for (int k = 0; k < 256; ++k) acc = fmaf(hr[k], W[k * 768 + col], acc);
        qkv[col] = acc;
    }
    __syncthreads();
    int b = row >> 5, s = row & 31;
    int hd_i = t >> 6, d = t & 63;
    size_t dst = ((size_t)(b * 4 + hd_i) * 32 + s) * 64 + d;
    int j = d >> 1;
    // inv_freq = 10000^(-2j/64) = 2^(-j * (2/64) * log2(10000))
    float freq = exp2f(-(float)j * 0.41524101186f);
    float ang = (float)s * freq;
    float sn, cs;
    sincosf(ang, &sn, &cs);
    {
        float xe = qkv[t & ~1], xo = qkv[t | 1];
        qb[dst] = (d & 1) ? (xo * cs + xe * sn) : (xe * cs - xo * sn);
    }
    {
        float xe = qkv[256 + (t & ~1)], xo = qkv[256 + (t | 1)];
        kb[dst] = (d & 1) ? (xo * cs + xe * sn) : (xe * cs - xo * sn);
    }
    vb[dst] = qkv[512 + t];
}

// ---------- attention per (b, head): softmax(mask(QK^T*scale)) @ V ----------
__global__ __launch_bounds__(256) void k_attn(
    const float* __restrict__ qb, const float* __restrict__ kb, const float* __restrict__ vb,
    const float* __restrict__ padf, float* __restrict__ y)
{
    __shared__ float Q[32][65], K[32][65], V[32][65], P[32][33];
    int bh = blockIdx.x;              // b*4 + h
    int b = bh >> 2, hh = bh & 3;
    int t = threadIdx.x;
    #pragma unroll
    for (int i = 0; i < 8; ++i) {
        int idx = t + i * 256;        // 0..2047
        int r = idx >> 6, d = idx & 63;
        Q[r][d] = qb[(size_t)bh * 2048 + idx];
        K[r][d] = kb[(size_t)bh * 2048 + idx];
        V[r][d] = vb[(size_t)bh * 2048 + idx];
    }
    __syncthreads();
    int r = t >> 3, k8 = t & 7;
    #pragma unroll
    for (int i = 0; i < 4; ++i) {
        int kk = k8 + i * 8;
        float acc = 0.f;
        #pragma unroll
        for (int d = 0; d < 64; ++d) acc = fmaf(Q[r][d], K[kk][d], acc);
        acc *= 0.125f;
        bool ok = (kk <= r) && (padf[b * 32 + kk] != 0.f);
        P[r][kk] = ok ? acc : -1e9f;
    }
    __syncthreads();
    if (t < 32) {
        float mx = -1e30f;
        #pragma unroll
        for (int kk = 0; kk < 32; ++kk) mx = fmaxf(mx, P[t][kk]);
        float sum = 0.f, e[32];
        #pragma unroll
        for (int kk = 0; kk < 32; ++kk) { e[kk] = __expf(P[t][kk] - mx); sum += e[kk]; }
        float inv = 1.f / sum;
        #pragma unroll
        for (int kk = 0; kk < 32; ++kk) P[t][kk] = e[kk] * inv;
    }
    __syncthreads();
    int d0 = (t & 7) * 8;
    float o[8] = {0.f, 0.f, 0.f, 0.f, 0.f, 0.f, 0.f, 0.f};
    for (int kk = 0; kk < 32; ++kk) {
        float a = P[r][kk];
        #pragma unroll
        for (int jj = 0; jj < 8; ++jj) o[jj] = fmaf(a, V[kk][d0 + jj], o[jj]);
    }
    float* dst = y + ((size_t)(b * 32 + r) * 256 + hh * 64 + d0);
    #pragma unroll
    for (int jj = 0; jj < 8; ++jj) dst[jj] = o[jj];
}

// ---------- attn out-proj + pad mask + LN + residual (in-place h) ----------
__global__ __launch_bounds__(256) void k_attn_out(
    const float* __restrict__ y, const float* __restrict__ W, const float* __restrict__ bvec,
    const float* __restrict__ padf, const float* __restrict__ lns, const float* __restrict__ lnb,
    float* __restrict__ h)
{
    __shared__ float yr[256];
    int row = blockIdx.x, t = threadIdx.x;
    yr[t] = y[row * 256 + t];
    __syncthreads();
    float acc = bvec[t];
    #pragma unroll 8
    for (int k = 0; k < 256; ++k) acc = fmaf(yr[k], W[k * 256 + t], acc);
    acc *= padf[row];
    float2 sq = block_sum2(acc, acc * acc);
    float m = sq.x * (1.f / 256.f);
    float var = sq.y * (1.f / 256.f) - m * m;
    float res = h[row * 256 + t];
    h[row * 256 + t] = (acc - m) * rsqrtf(var + LN_EPS) * lns[t] + lnb[t] + res;
}

// ---------- MLP up (256->512) + ReLU ----------
__global__ __launch_bounds__(256) void k_mlp_up(
    const float* __restrict__ h, const float* __restrict__ W, float* __restrict__ u)
{
    __shared__ float hr[256];
    int row = blockIdx.x, t = threadIdx.x;
    hr[t] = h[row * 256 + t];
    __syncthreads();
    float a0 = 0.f, a1 = 0.f;
    #pragma unroll 8
    for (int k = 0; k < 256; ++k) {
        float hk = hr[k];
        a0 = fmaf(hk, W[k * 512 + t], a0);
        a1 = fmaf(hk, W[k * 512 + 256 + t], a1);
    }
    u[row * 512 + t] = fmaxf(a0, 0.f);
    u[row * 512 + 256 + t] = fmaxf(a1, 0.f);
}

// ---------- MLP down (512->256) + LN + residual (in-place h) ----------
__global__ __launch_bounds__(256) void k_mlp_down(
    const float* __restrict__ u, const float* __restrict__ W,
    const float* __restrict__ lns, const float* __restrict__ lnb, float* __restrict__ h)
{
    __shared__ float ur[512];
    int row = blockIdx.x, t = threadIdx.x;
    ur[t] = u[row * 512 + t];
    ur[t + 256] = u[row * 512 + 256 + t];
    __syncthreads();
    float acc = 0.f;
    #pragma unroll 8
    for (int k = 0; k < 512; ++k) acc = fmaf(ur[k], W[k * 256 + t], acc);
    float2 sq = block_sum2(acc, acc * acc);
    float m = sq.x * (1.f / 256.f);
    float var = sq.y * (1.f / 256.f) - m * m;
    float res = h[row * 256 + t];
    h[row * 256 + t] = (acc - m) * rsqrtf(var + LN_EPS) * lns[t] + lnb[t] + res;
}

// ---------- head (256->18) ----------
__global__ __launch_bounds__(256) void k_head(
    const float* __restrict__ h, const float* __restrict__ W, const float* __restrict__ b,
    float* __restrict__ out)
{
    __shared__ float hr[256];
    int row = blockIdx.x, t = threadIdx.x;
    hr[t] = h[row * 256 + t];
    __syncthreads();
    if (t < 18) {
        float acc = b[t];
        #pragma unroll 8
        for (int k = 0; k < 256; ++k) acc = fmaf(hr[k], W[k * 18 + t], acc);
        out[row * 18 + t] = acc;
    }
}

extern "C" void kernel_launch(void* const* d_in, const int* in_sizes, int n_in,
                              void* d_out, int out_size, void* d_ws, size_t ws_size,
                              hipStream_t stream)
{
    (void)in_sizes; (void)n_in; (void)out_size; (void)ws_size;
    const float* x   = (const float*)d_in[0];
    const unsigned char* pad = (const unsigned char*)d_in[1];
    const float* c0w = (const float*)d_in[2];
    const float* c0b = (const float*)d_in[3];
    const float* l0s = (const float*)d_in[4];
    const float* l0b = (const float*)d_in[5];
    const float* c1w = (const float*)d_in[6];
    const float* c1b = (const float*)d_in[7];
    const float* l1s = (const float*)d_in[8];
    const float* l1b = (const float*)d_in[9];
    const float* pw  = (const float*)d_in[10];
    const float* pb  = (const float*)d_in[11];
    const float* lps = (const float*)d_in[12];
    const float* lpb = (const float*)d_in[13];
    const float* qkvw = (const float*)d_in[14];
    const float* qkvb = (const float*)d_in[15];
    const float* ow  = (const float*)d_in[16];
    const float* obv = (const float*)d_in[17];
    const float* las = (const float*)d_in[18];
    const float* lab = (const float*)d_in[19];
    const float* upw = (const float*)d_in[20];
    const float* dww = (const float*)d_in[21];
    const float* lms = (const float*)d_in[22];
    const float* lmb = (const float*)d_in[23];
    const float* hw  = (const float*)d_in[24];
    const float* hb  = (const float*)d_in[25];
    float* out = (float*)d_out;

    char* ws = (char*)d_ws;
    size_t off = 0;
    auto alloc = [&](size_t bytes) -> void* {
        void* p = ws + off;
        off = (off + bytes + 255) & ~(size_t)255;
        return p;
    };
    unsigned short* a0  = (unsigned short*)alloc((size_t)512 * 7056 * 32 * 2);
    unsigned short* wtb = (unsigned short*)alloc(18432 * 2);
    float* pooled = (float*)alloc(512 * 64 * 4);
    float* padf   = (float*)alloc(512 * 4);
    float* h      = (float*)alloc(512 * 256 * 4);
    float* qb     = (float*)alloc(512 * 256 * 4);
    float* kb     = (float*)alloc(512 * 256 * 4);
    float* vb     = (float*)alloc(512 * 256 * 4);
    float* yb     = (float*)alloc(512 * 256 * 4);
    float* ub     = (float*)alloc(512 * 512 * 4);

    hipMemsetAsync(pooled, 0, 512 * 64 * 4, stream);
    k_pad<<<1, 512, 0, stream>>>(pad, padf);
    k_conv0<<<14112, 256, 0, stream>>>(x, c0w, c0b, l0s, l0b, a0);
    k_wprep<<<72, 256, 0, stream>>>(c1w, wtb);
    k_conv1<<<14336, 256, 0, stream>>>(a0, wtb, c1b, l1s, l1b, pooled);
    k_pool_proj<<<512, 256, 0, stream>>>(pooled, pw, pb, lps, lpb, h);
    for (int i = 0; i < 2; ++i) {
        k_qkv_rope<<<512, 256, 0, stream>>>(h, qkvw + (size_t)i * 256 * 768, qkvb + i * 768, qb, kb, vb);
        k_attn<<<64, 256, 0, stream>>>(qb, kb, vb, padf, yb);
        k_attn_out<<<512, 256, 0, stream>>>(yb, ow + (size_t)i * 256 * 256, obv + i * 256,
                                            padf, las + i * 256, lab + i * 256, h);
        k_mlp_up<<<512, 256, 0, stream>>>(h, upw + (size_t)i * 256 * 512, ub);
        k_mlp_down<<<512, 256, 0, stream>>>(ub, dww + (size_t)i * 512 * 256,
                                            lms + i * 256, lmb + i * 256, h);
    }
    k_head<<<512, 256, 0, stream>>>(h, hw, hb, out);
}

// Round 4
// 549.912 us; speedup vs baseline: 1.7982x; 1.1892x over previous
//
#include <hip/hip_runtime.h>
#include <hip/hip_bf16.h>

#define LN_EPS 1e-6f

typedef __attribute__((ext_vector_type(8))) short bf16x8;
typedef __attribute__((ext_vector_type(4))) float fx4;

__device__ __forceinline__ unsigned short f2bf(float f) {
    union { __hip_bfloat16 b; unsigned short u; } cv;
    cv.b = __float2bfloat16(f);
    return cv.u;
}

// ---------- pad dtype detector: u8 bool vs int32 ----------
__global__ void k_pad(const unsigned char* __restrict__ p, float* __restrict__ padf) {
    __shared__ int cnt;
    int t = threadIdx.x;                  // 512 threads
    if (t == 0) cnt = 0;
    __syncthreads();
    if (p[t]) atomicAdd(&cnt, 1);
    __syncthreads();
    float v;
    if (cnt > 256) v = p[t] ? 1.f : 0.f;                       // u8 bools
    else           v = ((const int*)p)[t] ? 1.f : 0.f;          // int32 per elem
    padf[t] = v;
}

// ---------- conv0 (3x3, 4->32) + bias + LN(32) + ReLU -> bf16 ----------
__global__ __launch_bounds__(256) void k_conv0(
    const float* __restrict__ x, const float* __restrict__ w,
    const float* __restrict__ bias, const float* __restrict__ lns, const float* __restrict__ lnb,
    unsigned short* __restrict__ a0)
{
    int pid = blockIdx.x * 256 + threadIdx.x;   // 512*7056 exactly
    int img = pid / 7056;
    int p = pid - img * 7056;
    int py = p / 84;
    int px = p - py * 84;

    float acc[32];
    #pragma unroll
    for (int c = 0; c < 32; ++c) acc[c] = bias[c];

    #pragma unroll
    for (int dy = 0; dy < 3; ++dy) {
        int yy = py + dy - 1;
        if (yy < 0 || yy >= 84) continue;
        #pragma unroll
        for (int dx = 0; dx < 3; ++dx) {
            int xx = px + dx - 1;
            if (xx < 0 || xx >= 84) continue;
            float4 v = *reinterpret_cast<const float4*>(x + ((size_t)img * 7056 + yy * 84 + xx) * 4);
            const float* wt = w + (dy * 3 + dx) * 128;   // (3,3,4,32)
            #pragma unroll
            for (int ci = 0; ci < 4; ++ci) {
                float xv = (&v.x)[ci];
                #pragma unroll
                for (int c = 0; c < 32; ++c)
                    acc[c] = fmaf(xv, wt[ci * 32 + c], acc[c]);
            }
        }
    }
    float m = 0.f;
    #pragma unroll
    for (int c = 0; c < 32; ++c) m += acc[c];
    m *= (1.f / 32.f);
    float var = 0.f;
    #pragma unroll
    for (int c = 0; c < 32; ++c) { float d = acc[c] - m; var = fmaf(d, d, var); }
    var *= (1.f / 32.f);
    float inv = rsqrtf(var + LN_EPS);
    unsigned short ob[32];
    #pragma unroll
    for (int c = 0; c < 32; ++c) {
        float o = (acc[c] - m) * inv * lns[c] + lnb[c];
        ob[c] = f2bf(fmaxf(o, 0.f));
    }
    uint4* dst = reinterpret_cast<uint4*>(a0 + (size_t)pid * 32);
    #pragma unroll
    for (int g = 0; g < 4; ++g) {
        uint4 pk;
        pk.x = (unsigned)ob[g * 8 + 0] | ((unsigned)ob[g * 8 + 1] << 16);
        pk.y = (unsigned)ob[g * 8 + 2] | ((unsigned)ob[g * 8 + 3] << 16);
        pk.z = (unsigned)ob[g * 8 + 4] | ((unsigned)ob[g * 8 + 5] << 16);
        pk.w = (unsigned)ob[g * 8 + 6] | ((unsigned)ob[g * 8 + 7] << 16);
        dst[g] = pk;
    }
}

// ---------- conv1 weight repack: (3,3,32,64) f32 -> wtb[tap][co][kg][j] bf16 ----------
__global__ void k_wprep(const float* __restrict__ w, unsigned short* __restrict__ wtb) {
    int idx = blockIdx.x * 256 + threadIdx.x;   // 18432 exactly
    int j  = idx & 7;
    int kg = (idx >> 3) & 3;
    int co = (idx >> 5) & 63;
    int tp = idx >> 11;
    float v = w[((size_t)tp * 32 + kg * 8 + j) * 64 + co];
    wtb[idx] = f2bf(v);
}

// ---------- tail weight pack: all transformer weights -> bf16 col-major [N][K] ----------
// layout in wpk (elems): qkv 2*768*256 | out 2*256*256 | up 2*512*256 | down 2*256*512 | proj 256*64
__global__ void k_wpack(const float* __restrict__ qkvw, const float* __restrict__ ow,
                        const float* __restrict__ upw, const float* __restrict__ dww,
                        const float* __restrict__ pw, unsigned short* __restrict__ wpk)
{
    int idx = blockIdx.x * 256 + threadIdx.x;
    if (idx >= 1064960) return;
    float v;
    if (idx < 393216) {
        int l = idx / 196608, rm = idx % 196608, n = rm >> 8, k = rm & 255;
        v = qkvw[((size_t)l * 256 + k) * 768 + n];
    } else if (idx < 524288) {
        int r = idx - 393216, l = r >> 16, rm = r & 65535, n = rm >> 8, k = rm & 255;
        v = ow[((size_t)l * 256 + k) * 256 + n];
    } else if (idx < 786432) {
        int r = idx - 524288, l = r >> 17, rm = r & 131071, n = rm >> 8, k = rm & 255;
        v = upw[((size_t)l * 256 + k) * 512 + n];
    } else if (idx < 1048576) {
        int r = idx - 786432, l = r >> 17, rm = r & 131071, n = rm >> 9, k = rm & 511;
        v = dww[((size_t)l * 512 + k) * 256 + n];
    } else {
        int r = idx - 1048576, n = r >> 6, k = r & 63;
        v = pw[k * 256 + n];
    }
    wpk[idx] = f2bf(v);
}

// ---------- conv1 (3x3, 32->64) LDS-staged implicit GEMM + bias + LN(64) + ReLU + mean-pool ----------
__global__ __launch_bounds__(256, 3) void k_conv1(
    const unsigned short* __restrict__ a0, const unsigned short* __restrict__ wtb,
    const float* __restrict__ bias, const float* __restrict__ lns, const float* __restrict__ lnb,
    float* __restrict__ pooled)
{
    __shared__ __align__(16) unsigned short At[4][5][86][8];   // 27520 B
    __shared__ float pool_w[4][64];
    const int tid = threadIdx.x;
    const int img = blockIdx.x / 28;
    const int rg  = blockIdx.x - img * 28;
    const int y0  = rg * 3;

    if (tid >= 64 && tid < 104) {
        int z = tid - 64;
        int zk = z / 10, rem = z - zk * 10, zr = rem >> 1, side = rem & 1;
        *reinterpret_cast<uint4*>(&At[zk][zr][side ? 85 : 0][0]) = (uint4){0, 0, 0, 0};
    }
    {
        const size_t ibase = (size_t)img * 7056 * 32;
        #pragma unroll
        for (int it = 0; it < 7; ++it) {
            int i = tid + it * 256;
            if (i < 1680) {
                int skg = i & 3, t2 = i >> 2;
                int r = t2 / 84, px = t2 - r * 84;
                int gy = y0 - 1 + r;
                uint4 v = (uint4){0, 0, 0, 0};
                if (gy >= 0 && gy < 84)
                    v = *reinterpret_cast<const uint4*>(a0 + ibase + (size_t)(gy * 84 + px) * 32 + skg * 8);
                *reinterpret_cast<uint4*>(&At[skg][r][px + 1][0]) = v;
            }
        }
    }
    __syncthreads();

    const int lane = tid & 63;
    const int wv = tid >> 6;
    const int lo = lane & 15;
    const int kg = lane >> 4;

    int abase[4];
    #pragma unroll
    for (int m = 0; m < 4; ++m) {
        int pl = wv * 64 + m * 16 + lo;
        if (pl > 251) pl = 251;
        int rl = pl / 84;
        int c = pl - rl * 84;
        abase[m] = ((kg * 5 + rl) * 86 + c) * 8;
    }

    fx4 acc[4][4];
    #pragma unroll
    for (int m = 0; m < 4; ++m)
        #pragma unroll
        for (int n = 0; n < 4; ++n) acc[m][n] = (fx4){0.f, 0.f, 0.f, 0.f};

    const unsigned short* Abase = &At[0][0][0][0];
    #pragma unroll
    for (int dy = 0; dy < 3; ++dy) {
        #pragma unroll
        for (int dx = 0; dx < 3; ++dx) {
            const int t = dy * 3 + dx;
            bf16x8 Bf[4];
            #pragma unroll
            for (int n = 0; n < 4; ++n)
                Bf[n] = *reinterpret_cast<const bf16x8*>(
                    wtb + (size_t)((t * 64 + n * 16 + lo) * 4 + kg) * 8);
            #pragma unroll
            for (int m = 0; m < 4; ++m) {
                bf16x8 Af = *reinterpret_cast<const bf16x8*>(Abase + abase[m] + (dy * 86 + dx) * 8);
                #pragma unroll
                for (int n = 0; n < 4; ++n)
                    acc[m][n] = __builtin_amdgcn_mfma_f32_16x16x32_bf16(Af, Bf[n], acc[m][n], 0, 0, 0);
            }
        }
    }

    float bs[4], ss[4], bb[4];
    #pragma unroll
    for (int n = 0; n < 4; ++n) {
        int c = n * 16 + lo;
        bs[n] = bias[c]; ss[n] = lns[c]; bb[n] = lnb[c];
    }
    float pv[4] = {0.f, 0.f, 0.f, 0.f};
    #pragma unroll
    for (int m = 0; m < 4; ++m) {
        #pragma unroll
        for (int r = 0; r < 4; ++r) {
            float v0 = acc[m][0][r] + bs[0], v1 = acc[m][1][r] + bs[1];
            float v2 = acc[m][2][r] + bs[2], v3 = acc[m][3][r] + bs[3];
            float s = v0 + v1 + v2 + v3;
            float q = v0 * v0 + v1 * v1 + v2 * v2 + v3 * v3;
            #pragma unroll
            for (int off = 1; off < 16; off <<= 1) {
                s += __shfl_xor(s, off);
                q += __shfl_xor(q, off);
            }
            float mn = s * (1.f / 64.f);
            float var = q * (1.f / 64.f) - mn * mn;
            float inv = rsqrtf(var + LN_EPS);
            int pix = wv * 64 + m * 16 + kg * 4 + r;
            float valid = (pix < 252) ? 1.f : 0.f;
            pv[0] += fmaxf((v0 - mn) * inv * ss[0] + bb[0], 0.f) * valid;
            pv[1] += fmaxf((v1 - mn) * inv * ss[1] + bb[1], 0.f) * valid;
            pv[2] += fmaxf((v2 - mn) * inv * ss[2] + bb[2], 0.f) * valid;
            pv[3] += fmaxf((v3 - mn) * inv * ss[3] + bb[3], 0.f) * valid;
        }
    }
    #pragma unroll
    for (int n = 0; n < 4; ++n) {
        float v = pv[n];
        v += __shfl_xor(v, 16);
        v += __shfl_xor(v, 32);
        if (lane < 16) pool_w[wv][n * 16 + lane] = v;
    }
    __syncthreads();
    if (tid < 64) {
        float s = pool_w[0][tid] + pool_w[1][tid] + pool_w[2][tid] + pool_w[3][tid];
        atomicAdd(&pooled[img * 64 + tid], s);
    }
}

// ================= fused per-batch transformer =================
// Block = one batch element (32 seq rows). 512 threads = 8 waves.
// MFMA convention (verified in k_conv1): A row-major [M][K] (lda elems), B packed
// col-major [N][K] (ldb elems); A-frag row=lane&15, k=(lane>>4)*8+j; B-frag col=lane&15;
// D: col = ntile*16 + (lane&15), row = mtile*16 + (lane>>4)*4 + reg.

template<int MT, int NT, int KS>
__device__ __forceinline__ void mfma_gemm(
    const unsigned short* A, int lda, int m0,
    const unsigned short* B, int ldb, int nt0,
    fx4 (&acc)[MT][NT], int lane)
{
    const int lo = lane & 15, kg = lane >> 4;
    #pragma unroll
    for (int ks = 0; ks < KS; ++ks) {
        const int k = ks * 32 + kg * 8;
        bf16x8 af[MT];
        #pragma unroll
        for (int m = 0; m < MT; ++m)
            af[m] = *reinterpret_cast<const bf16x8*>(A + (size_t)((m0 + m) * 16 + lo) * lda + k);
        #pragma unroll
        for (int n = 0; n < NT; ++n) {
            bf16x8 bf = *reinterpret_cast<const bf16x8*>(B + (size_t)((nt0 + n) * 16 + lo) * ldb + k);
            #pragma unroll
            for (int m = 0; m < MT; ++m)
                acc[m][n] = __builtin_amdgcn_mfma_f32_16x16x32_bf16(af[m], bf, acc[m][n], 0, 0, 0);
        }
    }
}

__device__ __forceinline__ void ln_update(
    const float* outs /*[32][257] LDS*/, float* hs, unsigned short* hs_b,
    const float* gs, const float* gb, bool resid, int w, int lane)
{
    #pragma unroll
    for (int i = 0; i < 4; ++i) {
        int r = w * 4 + i;
        float x[4], s = 0.f, q = 0.f;
        #pragma unroll
        for (int j = 0; j < 4; ++j) {
            x[j] = outs[r * 257 + lane + 64 * j];
            s += x[j]; q += x[j] * x[j];
        }
        #pragma unroll
        for (int off = 1; off < 64; off <<= 1) {
            s += __shfl_xor(s, off);
            q += __shfl_xor(q, off);
        }
        float mn = s * (1.f / 256.f);
        float inv = rsqrtf(q * (1.f / 256.f) - mn * mn + LN_EPS);
        #pragma unroll
        for (int j = 0; j < 4; ++j) {
            int c = lane + 64 * j;
            float nv = (x[j] - mn) * inv * gs[c] + gb[c];
            if (resid) nv += hs[r * 256 + c];
            hs[r * 256 + c] = nv;
            hs_b[r * 264 + c] = f2bf(nv);
        }
    }
}

__global__ __launch_bounds__(512) void k_xformer(
    const float* __restrict__ pooled, const float* __restrict__ padf,
    const unsigned short* __restrict__ wpk,
    const float* __restrict__ pb, const float* __restrict__ lps, const float* __restrict__ lpb,
    const float* __restrict__ qkvb, const float* __restrict__ obv,
    const float* __restrict__ las, const float* __restrict__ lab,
    const float* __restrict__ lms, const float* __restrict__ lmb,
    const float* __restrict__ hw, const float* __restrict__ hb,
    float* __restrict__ out)
{
    // LDS map (bytes): hs f32[32][256] @0 (32768) | hs_b bf16[32][264] @32768 (16896)
    // R1 @49664 (36864): q_s bf16[4][32][72], k_s bf16[4][32][72]; aliases: pa[h] over q_s[h], us_b[32][520]
    // R2 @86528 (37376): v_cm bf16[4][64][40] (20480), ys_b bf16[32][264] @107008 (16896);
    //                    aliases: outs f32[32][257] @86528 (32896), pool_b bf16[32][72] @86528
    // padc f32[32] @123904
    __shared__ __align__(16) char smem[124032];
    float* hs = (float*)(smem);
    unsigned short* hs_b = (unsigned short*)(smem + 32768);
    unsigned short* R1 = (unsigned short*)(smem + 49664);
    unsigned short* q_s = R1;                   // per-head stride 2304 elems
    unsigned short* k_s = R1 + 9216;
    unsigned short* us_b = R1;                  // [32][520]
    unsigned short* v_cm = (unsigned short*)(smem + 86528);    // [4][64][40], head stride 2560
    unsigned short* ys_b = (unsigned short*)(smem + 107008);   // [32][264]
    float* outs = (float*)(smem + 86528);       // [32][257]
    unsigned short* pool_b = (unsigned short*)(smem + 86528);  // [32][72]
    float* padc = (float*)(smem + 123904);

    const int b = blockIdx.x, t = threadIdx.x;
    const int w = t >> 6, lane = t & 63, lo = lane & 15, kg = lane >> 4;

    // ---- P0: load pad flags + pooled (mean) ----
    if (t < 32) padc[t] = padf[b * 32 + t];
    for (int i = t; i < 2048; i += 512) {
        int r = i >> 6, k = i & 63;
        pool_b[r * 72 + k] = f2bf(pooled[((size_t)b * 32 + r) * 64 + k] * (1.f / 7056.f));
    }
    __syncthreads();

    // ---- P1: proj (64->256) + bias + LN -> hs ----
    {
        fx4 acc[1][4];
        #pragma unroll
        for (int n = 0; n < 4; ++n) acc[0][n] = (fx4){0.f, 0.f, 0.f, 0.f};
        int m0 = w & 1, nt0 = (w >> 1) * 4;
        mfma_gemm<1, 4, 2>(pool_b, 72, m0, wpk + 1048576, 64, nt0, acc, lane);
        __syncthreads();   // pool_b dead; outs aliases it
        #pragma unroll
        for (int n = 0; n < 4; ++n) {
            int c = (nt0 + n) * 16 + lo;
            float bias = pb[c];
            #pragma unroll
            for (int rg = 0; rg < 4; ++rg)
                outs[(m0 * 16 + kg * 4 + rg) * 257 + c] = acc[0][n][rg] + bias;
        }
        __syncthreads();
        ln_update(outs, hs, hs_b, lps, lpb, false, w, lane);
        __syncthreads();
    }

    // ---- transformer layers ----
    for (int l = 0; l < 2; ++l) {
        const unsigned short* wq = wpk + (size_t)l * 196608;
        const unsigned short* wo = wpk + 393216 + (size_t)l * 65536;
        const unsigned short* wu = wpk + 524288 + (size_t)l * 131072;
        const unsigned short* wd = wpk + 786432 + (size_t)l * 131072;

        // qkv (256 -> 768) + bias + RoPE -> q_s, k_s, v_cm
        {
            fx4 acc[2][6];
            #pragma unroll
            for (int m = 0; m < 2; ++m)
                #pragma unroll
                for (int n = 0; n < 6; ++n) acc[m][n] = (fx4){0.f, 0.f, 0.f, 0.f};
            int nt0 = w * 6;
            mfma_gemm<2, 6, 8>(hs_b, 264, 0, wq, 256, nt0, acc, lane);
            #pragma unroll
            for (int n = 0; n < 6; ++n) {
                int c = (nt0 + n) * 16 + lo;
                int kind = c >> 8, cl = c & 255, h = cl >> 6, d = cl & 63;
                float bias = qkvb[l * 768 + c];
                if (kind < 2) {
                    int j = d >> 1;
                    float freq = exp2f(-(float)j * 0.41524101186f);
                    unsigned short* dst = (kind ? k_s : q_s) + h * 2304;
                    #pragma unroll
                    for (int m = 0; m < 2; ++m)
                        #pragma unroll
                        for (int rg = 0; rg < 4; ++rg) {
                            float val = acc[m][n][rg] + bias;
                            float prt = __shfl_xor(val, 1);
                            int r = m * 16 + kg * 4 + rg;
                            float sn, cs;
                            __sincosf((float)r * freq, &sn, &cs);
                            float rv = (d & 1) ? (val * cs + prt * sn) : (val * cs - prt * sn);
                            dst[r * 72 + d] = f2bf(rv);
                        }
                } else {
                    #pragma unroll
                    for (int m = 0; m < 2; ++m)
                        #pragma unroll
                        for (int rg = 0; rg < 4; ++rg) {
                            int r = m * 16 + kg * 4 + rg;
                            v_cm[(h * 64 + d) * 40 + r] = f2bf(acc[m][n][rg] + bias);
                        }
                }
            }
            __syncthreads();
        }

        // scores = QK^T * scale, mask, softmax -> pa (aliases q_s)
        {
            int h = w >> 1, mt = w & 1;
            fx4 sc[1][2];
            sc[0][0] = (fx4){0.f, 0.f, 0.f, 0.f};
            sc[0][1] = (fx4){0.f, 0.f, 0.f, 0.f};
            mfma_gemm<1, 2, 2>(q_s + h * 2304, 72, mt, k_s + h * 2304, 72, 0, sc, lane);
            __syncthreads();    // all q_s reads done before pa overwrites
            unsigned short* pa = R1 + h * 2304;   // [32][40]
            float pad0 = padc[lo], pad1 = padc[16 + lo];
            #pragma unroll
            for (int rg = 0; rg < 4; ++rg) {
                int qr = mt * 16 + kg * 4 + rg;
                float v0 = (lo <= qr && pad0 != 0.f) ? sc[0][0][rg] * 0.125f : -1e9f;
                float v1 = ((16 + lo) <= qr && pad1 != 0.f) ? sc[0][1][rg] * 0.125f : -1e9f;
                float mx = fmaxf(v0, v1);
                #pragma unroll
                for (int off = 1; off < 16; off <<= 1) mx = fmaxf(mx, __shfl_xor(mx, off));
                float e0 = __expf(v0 - mx), e1 = __expf(v1 - mx);
                float sm = e0 + e1;
                #pragma unroll
                for (int off = 1; off < 16; off <<= 1) sm += __shfl_xor(sm, off);
                float inv = 1.f / sm;
                pa[qr * 40 + lo] = f2bf(e0 * inv);
                pa[qr * 40 + 16 + lo] = f2bf(e1 * inv);
            }
            __syncthreads();
        }

        // y = P @ V -> ys_b
        {
            int h = w >> 1, mt = w & 1;
            fx4 yv[1][4];
            #pragma unroll
            for (int n = 0; n < 4; ++n) yv[0][n] = (fx4){0.f, 0.f, 0.f, 0.f};
            mfma_gemm<1, 4, 1>(R1 + h * 2304, 40, mt, v_cm + h * 2560, 40, 0, yv, lane);
            #pragma unroll
            for (int n = 0; n < 4; ++n) {
                int d = n * 16 + lo;
                #pragma unroll
                for (int rg = 0; rg < 4; ++rg)
                    ys_b[(mt * 16 + kg * 4 + rg) * 264 + h * 64 + d] = f2bf(yv[0][n][rg]);
            }
            __syncthreads();
        }

        // out-proj (256->256) + bias + pad-mask -> outs; LN + residual -> hs
        {
            fx4 ac[2][2];
            #pragma unroll
            for (int m = 0; m < 2; ++m) { ac[m][0] = (fx4){0.f,0.f,0.f,0.f}; ac[m][1] = (fx4){0.f,0.f,0.f,0.f}; }
            mfma_gemm<2, 2, 8>(ys_b, 264, 0, wo, 256, w * 2, ac, lane);
            __syncthreads();   // ys_b/v_cm dead; outs aliases them
            #pragma unroll
            for (int n = 0; n < 2; ++n) {
                int c = (w * 2 + n) * 16 + lo;
                float bias = obv[l * 256 + c];
                #pragma unroll
                for (int m = 0; m < 2; ++m)
                    #pragma unroll
                    for (int rg = 0; rg < 4; ++rg) {
                        int r = m * 16 + kg * 4 + rg;
                        outs[r * 257 + c] = (ac[m][n][rg] + bias) * padc[r];
                    }
            }
            __syncthreads();
            ln_update(outs, hs, hs_b, las + l * 256, lab + l * 256, true, w, lane);
            __syncthreads();
        }

        // mlp up (256->512) + ReLU -> us_b
        {
            fx4 au[2][4];
            #pragma unroll
            for (int m = 0; m < 2; ++m)
                #pragma unroll
                for (int n = 0; n < 4; ++n) au[m][n] = (fx4){0.f, 0.f, 0.f, 0.f};
            mfma_gemm<2, 4, 8>(hs_b, 264, 0, wu, 256, w * 4, au, lane);
            #pragma unroll
            for (int n = 0; n < 4; ++n) {
                int c = (w * 4 + n) * 16 + lo;
                #pragma unroll
                for (int m = 0; m < 2; ++m)
                    #pragma unroll
                    for (int rg = 0; rg < 4; ++rg)
                        us_b[(m * 16 + kg * 4 + rg) * 520 + c] = f2bf(fmaxf(au[m][n][rg], 0.f));
            }
            __syncthreads();
        }

        // mlp down (512->256) -> outs; LN + residual -> hs
        {
            fx4 ad[2][2];
            #pragma unroll
            for (int m = 0; m < 2; ++m) { ad[m][0] = (fx4){0.f,0.f,0.f,0.f}; ad[m][1] = (fx4){0.f,0.f,0.f,0.f}; }
            mfma_gemm<2, 2, 16>(us_b, 520, 0, wd, 512, w * 2, ad, lane);
            #pragma unroll
            for (int n = 0; n < 2; ++n) {
                int c = (w * 2 + n) * 16 + lo;
                #pragma unroll
                for (int m = 0; m < 2; ++m)
                    #pragma unroll
                    for (int rg = 0; rg < 4; ++rg)
                        outs[(m * 16 + kg * 4 + rg) * 257 + c] = ad[m][n][rg];
            }
            __syncthreads();
            ln_update(outs, hs, hs_b, lms + l * 256, lmb + l * 256, true, w, lane);
            __syncthreads();
        }
    }

    // ---- head (256->18) ----
    for (int idx = t; idx < 576; idx += 512) {
        int r = idx / 18, a = idx - r * 18;
        float acch = hb[a];
        #pragma unroll 8
        for (int k = 0; k < 256; ++k) acch = fmaf(hs[r * 256 + k], hw[k * 18 + a], acch);
        out[((size_t)b * 32 + r) * 18 + a] = acch;
    }
}

extern "C" void kernel_launch(void* const* d_in, const int* in_sizes, int n_in,
                              void* d_out, int out_size, void* d_ws, size_t ws_size,
                              hipStream_t stream)
{
    (void)in_sizes; (void)n_in; (void)out_size; (void)ws_size;
    const float* x   = (const float*)d_in[0];
    const unsigned char* pad = (const unsigned char*)d_in[1];
    const float* c0w = (const float*)d_in[2];
    const float* c0b = (const float*)d_in[3];
    const float* l0s = (const float*)d_in[4];
    const float* l0b = (const float*)d_in[5];
    const float* c1w = (const float*)d_in[6];
    const float* c1b = (const float*)d_in[7];
    const float* l1s = (const float*)d_in[8];
    const float* l1b = (const float*)d_in[9];
    const float* pw  = (const float*)d_in[10];
    const float* pb  = (const float*)d_in[11];
    const float* lps = (const float*)d_in[12];
    const float* lpb = (const float*)d_in[13];
    const float* qkvw = (const float*)d_in[14];
    const float* qkvb = (const float*)d_in[15];
    const float* ow  = (const float*)d_in[16];
    const float* obv = (const float*)d_in[17];
    const float* las = (const float*)d_in[18];
    const float* lab = (const float*)d_in[19];
    const float* upw = (const float*)d_in[20];
    const float* dww = (const float*)d_in[21];
    const float* lms = (const float*)d_in[22];
    const float* lmb = (const float*)d_in[23];
    const float* hw  = (const float*)d_in[24];
    const float* hb  = (const float*)d_in[25];
    float* out = (float*)d_out;

    char* ws = (char*)d_ws;
    size_t off = 0;
    auto alloc = [&](size_t bytes) -> void* {
        void* p = ws + off;
        off = (off + bytes + 255) & ~(size_t)255;
        return p;
    };
    unsigned short* a0  = (unsigned short*)alloc((size_t)512 * 7056 * 32 * 2);
    unsigned short* wtb = (unsigned short*)alloc(18432 * 2);
    unsigned short* wpk = (unsigned short*)alloc((size_t)1064960 * 2);
    float* pooled = (float*)alloc(512 * 64 * 4);
    float* padf   = (float*)alloc(512 * 4);

    hipMemsetAsync(pooled, 0, 512 * 64 * 4, stream);
    k_pad<<<1, 512, 0, stream>>>(pad, padf);
    k_wprep<<<72, 256, 0, stream>>>(c1w, wtb);
    k_wpack<<<4160, 256, 0, stream>>>(qkvw, ow, upw, dww, pw, wpk);
    k_conv0<<<14112, 256, 0, stream>>>(x, c0w, c0b, l0s, l0b, a0);
    k_conv1<<<14336, 256, 0, stream>>>(a0, wtb, c1b, l1s, l1b, pooled);
    k_xformer<<<16, 512, 0, stream>>>(pooled, padf, wpk, pb, lps, lpb,
                                      qkvb, obv, las, lab, lms, lmb, hw, hb, out);
}

// Round 5
// 534.820 us; speedup vs baseline: 1.8490x; 1.0282x over previous
//
#include <hip/hip_runtime.h>
#include <hip/hip_bf16.h>

#define LN_EPS 1e-6f

typedef __attribute__((ext_vector_type(8))) short bf16x8;
typedef __attribute__((ext_vector_type(4))) float fx4;

struct U8 { union { bf16x8 v; uint2 p[2]; }; };

__device__ __forceinline__ unsigned short f2bf(float f) {
    union { __hip_bfloat16 b; unsigned short u; } cv;
    cv.b = __float2bfloat16(f);
    return cv.u;
}

// ---------- pad dtype detector: u8 bool vs int32 ----------
__global__ void k_pad(const unsigned char* __restrict__ p, float* __restrict__ padf) {
    __shared__ int cnt;
    int t = threadIdx.x;                  // 512 threads
    if (t == 0) cnt = 0;
    __syncthreads();
    if (p[t]) atomicAdd(&cnt, 1);
    __syncthreads();
    float v;
    if (cnt > 256) v = p[t] ? 1.f : 0.f;                       // u8 bools
    else           v = ((const int*)p)[t] ? 1.f : 0.f;          // int32 per elem
    padf[t] = v;
}

// ---------- weight repack ----------
// wtb[0..18432): conv1 (3,3,32,64) -> [tap][co][kg][j] bf16
// wtb[18432..20480): conv0 (3,3,4,32) -> wc0[ch 32][k 64] bf16, k=(tap<<2)|ci, zero-padded k>=36
__global__ void k_wprep(const float* __restrict__ w1, const float* __restrict__ w0,
                        unsigned short* __restrict__ wtb) {
    int idx = blockIdx.x * 256 + threadIdx.x;   // 20480 exactly
    if (idx < 18432) {
        int j  = idx & 7;
        int kg = (idx >> 3) & 3;
        int co = (idx >> 5) & 63;
        int tp = idx >> 11;
        wtb[idx] = f2bf(w1[((size_t)tp * 32 + kg * 8 + j) * 64 + co]);
    } else {
        int r = idx - 18432;
        int ch = r >> 6, k = r & 63;
        float v = 0.f;
        if (k < 36) v = w0[(size_t)k * 32 + ch];   // (tap*4+ci)*32+ch == k*32+ch
        wtb[idx] = f2bf(v);
    }
}

// ---------- tail weight pack: all transformer weights -> bf16 col-major [N][K] ----------
// layout in wpk (elems): qkv 2*768*256 | out 2*256*256 | up 2*512*256 | down 2*256*512 | proj 256*64
__global__ void k_wpack(const float* __restrict__ qkvw, const float* __restrict__ ow,
                        const float* __restrict__ upw, const float* __restrict__ dww,
                        const float* __restrict__ pw, unsigned short* __restrict__ wpk)
{
    int idx = blockIdx.x * 256 + threadIdx.x;
    if (idx >= 1064960) return;
    float v;
    if (idx < 393216) {
        int l = idx / 196608, rm = idx % 196608, n = rm >> 8, k = rm & 255;
        v = qkvw[((size_t)l * 256 + k) * 768 + n];
    } else if (idx < 524288) {
        int r = idx - 393216, l = r >> 16, rm = r & 65535, n = rm >> 8, k = rm & 255;
        v = ow[((size_t)l * 256 + k) * 256 + n];
    } else if (idx < 786432) {
        int r = idx - 524288, l = r >> 17, rm = r & 131071, n = rm >> 8, k = rm & 255;
        v = upw[((size_t)l * 256 + k) * 512 + n];
    } else if (idx < 1048576) {
        int r = idx - 786432, l = r >> 17, rm = r & 131071, n = rm >> 9, k = rm & 511;
        v = dww[((size_t)l * 512 + k) * 256 + n];
    } else {
        int r = idx - 1048576, n = r >> 6, k = r & 63;
        v = pw[k * 256 + n];
    }
    wpk[idx] = f2bf(v);
}

// ---------- fused conv0+conv1 + LN + ReLU + mean-pool ----------
// Block: one image x 3 output rows.
// Phase 0: stage x rows y0-2..y0+4 as bf16 -> xs[7][86][4] (zero-padded halo).
// Phase 1: conv0 via MFMA (K=64: 9 taps x 4ch zero-padded) + bias + LN(32) + ReLU -> At.
// Phase 2: conv1 implicit GEMM (unchanged from R3) + bias + LN(64) + ReLU + pool.
__global__ __launch_bounds__(256, 3) void k_conv1(
    const float* __restrict__ x, const unsigned short* __restrict__ wtb,
    const float* __restrict__ c0b, const float* __restrict__ l0s, const float* __restrict__ l0b,
    const float* __restrict__ bias, const float* __restrict__ lns, const float* __restrict__ lnb,
    float* __restrict__ pooled)
{
    __shared__ __align__(16) unsigned short At[4][5][86][8];   // 27520 B
    __shared__ __align__(16) unsigned short xs[7][86][4];      // 4816 B
    __shared__ float pool_w[4][64];
    const int tid = threadIdx.x;
    const int img = blockIdx.x / 28;
    const int rg  = blockIdx.x - img * 28;
    const int y0  = rg * 3;

    const int lane = tid & 63;
    const int wv = tid >> 6;
    const int lo = lane & 15;
    const int kg = lane >> 4;

    // ---- phase 0: stage x (7 rows, bf16, halo-padded) + zero At/xs halo cols ----
    if (tid >= 64 && tid < 104) {
        int z = tid - 64;
        int zk = z / 10, rem = z - zk * 10, zr = rem >> 1, side = rem & 1;
        *reinterpret_cast<uint4*>(&At[zk][zr][side ? 85 : 0][0]) = (uint4){0, 0, 0, 0};
    }
    if (tid >= 104 && tid < 118) {
        int z = tid - 104, row = z >> 1, side = z & 1;
        *reinterpret_cast<uint2*>(&xs[row][side ? 85 : 0][0]) = (uint2){0, 0};
    }
    for (int i = tid; i < 588; i += 256) {
        int row = i / 84, c = i - row * 84;
        int gy = y0 - 2 + row;
        float4 v = (float4){0.f, 0.f, 0.f, 0.f};
        if (gy >= 0 && gy < 84)
            v = *reinterpret_cast<const float4*>(x + ((size_t)img * 7056 + gy * 84 + c) * 4);
        unsigned l32 = (unsigned)f2bf(v.x) | ((unsigned)f2bf(v.y) << 16);
        unsigned h32 = (unsigned)f2bf(v.z) | ((unsigned)f2bf(v.w) << 16);
        *reinterpret_cast<uint2*>(&xs[row][c + 1][0]) = (uint2){l32, h32};
    }
    __syncthreads();

    // ---- phase 1: conv0 via MFMA -> At ----
    {
        const unsigned short* wc0 = wtb + 18432;
        bf16x8 B0[2], B1[2];
        #pragma unroll
        for (int n = 0; n < 2; ++n) {
            B0[n] = *reinterpret_cast<const bf16x8*>(wc0 + (n * 16 + lo) * 64 + kg * 8);
            B1[n] = *reinterpret_cast<const bf16x8*>(wc0 + (n * 16 + lo) * 64 + 32 + kg * 8);
        }
        float cb0 = c0b[lo], cb1 = c0b[lo + 16];
        float s0g = l0s[lo], s1g = l0s[lo + 16];
        float b0g = l0b[lo], b1g = l0b[lo + 16];
        const int t0 = 2 * kg, t1 = 2 * kg + 1;
        const int dy0 = t0 / 3, dx0 = t0 % 3, dy1 = t1 / 3, dx1 = t1 % 3;
        const unsigned short* xsb = &xs[0][0][0];

        for (int it = 0; it < 7; ++it) {
            int tb = it * 4 + wv;
            if (tb >= 27) break;
            int px = tb * 16 + lo;
            int pxc = px < 420 ? px : 419;
            int r5 = pxc / 84, col = pxc - r5 * 84;
            U8 a0u, a1u;
            a0u.p[0] = *reinterpret_cast<const uint2*>(xsb + ((r5 + dy0) * 86 + col + dx0) * 4);
            a0u.p[1] = *reinterpret_cast<const uint2*>(xsb + ((r5 + dy1) * 86 + col + dx1) * 4);
            if (kg == 0)
                a1u.p[0] = *reinterpret_cast<const uint2*>(xsb + ((r5 + 2) * 86 + col + 2) * 4);
            else
                a1u.p[0] = (uint2){0, 0};
            a1u.p[1] = (uint2){0, 0};

            fx4 c2[2];
            c2[0] = (fx4){0.f, 0.f, 0.f, 0.f};
            c2[1] = (fx4){0.f, 0.f, 0.f, 0.f};
            c2[0] = __builtin_amdgcn_mfma_f32_16x16x32_bf16(a0u.v, B0[0], c2[0], 0, 0, 0);
            c2[0] = __builtin_amdgcn_mfma_f32_16x16x32_bf16(a1u.v, B1[0], c2[0], 0, 0, 0);
            c2[1] = __builtin_amdgcn_mfma_f32_16x16x32_bf16(a0u.v, B0[1], c2[1], 0, 0, 0);
            c2[1] = __builtin_amdgcn_mfma_f32_16x16x32_bf16(a1u.v, B1[1], c2[1], 0, 0, 0);

            #pragma unroll
            for (int rg2 = 0; rg2 < 4; ++rg2) {
                float v0 = c2[0][rg2] + cb0, v1 = c2[1][rg2] + cb1;
                float s = v0 + v1, q = v0 * v0 + v1 * v1;
                #pragma unroll
                for (int off = 1; off < 16; off <<= 1) {
                    s += __shfl_xor(s, off);
                    q += __shfl_xor(q, off);
                }
                float mn = s * (1.f / 32.f);
                float var = q * (1.f / 32.f) - mn * mn;
                float inv = rsqrtf(var + LN_EPS);
                float o0 = fmaxf((v0 - mn) * inv * s0g + b0g, 0.f);
                float o1 = fmaxf((v1 - mn) * inv * s1g + b1g, 0.f);
                int pxk = tb * 16 + kg * 4 + rg2;
                if (pxk < 420) {
                    int r5k = pxk / 84, ck = pxk - r5k * 84;
                    int yA = y0 - 1 + r5k;
                    bool gv = (unsigned)yA < 84u;
                    At[lo >> 3][r5k][ck + 1][lo & 7]       = gv ? f2bf(o0) : (unsigned short)0;
                    At[2 + (lo >> 3)][r5k][ck + 1][lo & 7] = gv ? f2bf(o1) : (unsigned short)0;
                }
            }
        }
    }
    __syncthreads();

    // ---- phase 2: conv1 implicit GEMM (unchanged) ----
    int abase[4];
    #pragma unroll
    for (int m = 0; m < 4; ++m) {
        int pl = wv * 64 + m * 16 + lo;
        if (pl > 251) pl = 251;
        int rl = pl / 84;
        int c = pl - rl * 84;
        abase[m] = ((kg * 5 + rl) * 86 + c) * 8;
    }

    fx4 acc[4][4];
    #pragma unroll
    for (int m = 0; m < 4; ++m)
        #pragma unroll
        for (int n = 0; n < 4; ++n) acc[m][n] = (fx4){0.f, 0.f, 0.f, 0.f};

    const unsigned short* Abase = &At[0][0][0][0];
    #pragma unroll
    for (int dy = 0; dy < 3; ++dy) {
        #pragma unroll
        for (int dx = 0; dx < 3; ++dx) {
            const int t = dy * 3 + dx;
            bf16x8 Bf[4];
            #pragma unroll
            for (int n = 0; n < 4; ++n)
                Bf[n] = *reinterpret_cast<const bf16x8*>(
                    wtb + (size_t)((t * 64 + n * 16 + lo) * 4 + kg) * 8);
            #pragma unroll
            for (int m = 0; m < 4; ++m) {
                bf16x8 Af = *reinterpret_cast<const bf16x8*>(Abase + abase[m] + (dy * 86 + dx) * 8);
                #pragma unroll
                for (int n = 0; n < 4; ++n)
                    acc[m][n] = __builtin_amdgcn_mfma_f32_16x16x32_bf16(Af, Bf[n], acc[m][n], 0, 0, 0);
            }
        }
    }

    // ---- phase 3: bias + LN(64) + ReLU + pool ----
    float bs[4], ss[4], bb[4];
    #pragma unroll
    for (int n = 0; n < 4; ++n) {
        int c = n * 16 + lo;
        bs[n] = bias[c]; ss[n] = lns[c]; bb[n] = lnb[c];
    }
    float pv[4] = {0.f, 0.f, 0.f, 0.f};
    #pragma unroll
    for (int m = 0; m < 4; ++m) {
        #pragma unroll
        for (int r = 0; r < 4; ++r) {
            float v0 = acc[m][0][r] + bs[0], v1 = acc[m][1][r] + bs[1];
            float v2 = acc[m][2][r] + bs[2], v3 = acc[m][3][r] + bs[3];
            float s = v0 + v1 + v2 + v3;
            float q = v0 * v0 + v1 * v1 + v2 * v2 + v3 * v3;
            #pragma unroll
            for (int off = 1; off < 16; off <<= 1) {
                s += __shfl_xor(s, off);
                q += __shfl_xor(q, off);
            }
            float mn = s * (1.f / 64.f);
            float var = q * (1.f / 64.f) - mn * mn;
            float inv = rsqrtf(var + LN_EPS);
            int pix = wv * 64 + m * 16 + kg * 4 + r;
            float valid = (pix < 252) ? 1.f : 0.f;
            pv[0] += fmaxf((v0 - mn) * inv * ss[0] + bb[0], 0.f) * valid;
            pv[1] += fmaxf((v1 - mn) * inv * ss[1] + bb[1], 0.f) * valid;
            pv[2] += fmaxf((v2 - mn) * inv * ss[2] + bb[2], 0.f) * valid;
            pv[3] += fmaxf((v3 - mn) * inv * ss[3] + bb[3], 0.f) * valid;
        }
    }
    #pragma unroll
    for (int n = 0; n < 4; ++n) {
        float v = pv[n];
        v += __shfl_xor(v, 16);
        v += __shfl_xor(v, 32);
        if (lane < 16) pool_w[wv][n * 16 + lane] = v;
    }
    __syncthreads();
    if (tid < 64) {
        float s = pool_w[0][tid] + pool_w[1][tid] + pool_w[2][tid] + pool_w[3][tid];
        atomicAdd(&pooled[img * 64 + tid], s);
    }
}

// ================= fused per-batch transformer =================
template<int MT, int NT, int KS>
__device__ __forceinline__ void mfma_gemm(
    const unsigned short* A, int lda, int m0,
    const unsigned short* B, int ldb, int nt0,
    fx4 (&acc)[MT][NT], int lane)
{
    const int lo = lane & 15, kg = lane >> 4;
    #pragma unroll
    for (int ks = 0; ks < KS; ++ks) {
        const int k = ks * 32 + kg * 8;
        bf16x8 af[MT];
        #pragma unroll
        for (int m = 0; m < MT; ++m)
            af[m] = *reinterpret_cast<const bf16x8*>(A + (size_t)((m0 + m) * 16 + lo) * lda + k);
        #pragma unroll
        for (int n = 0; n < NT; ++n) {
            bf16x8 bf = *reinterpret_cast<const bf16x8*>(B + (size_t)((nt0 + n) * 16 + lo) * ldb + k);
            #pragma unroll
            for (int m = 0; m < MT; ++m)
                acc[m][n] = __builtin_amdgcn_mfma_f32_16x16x32_bf16(af[m], bf, acc[m][n], 0, 0, 0);
        }
    }
}

__device__ __forceinline__ void ln_update(
    const float* outs /*[32][257] LDS*/, float* hs, unsigned short* hs_b,
    const float* gs, const float* gb, bool resid, int w, int lane)
{
    #pragma unroll
    for (int i = 0; i < 4; ++i) {
        int r = w * 4 + i;
        float x[4], s = 0.f, q = 0.f;
        #pragma unroll
        for (int j = 0; j < 4; ++j) {
            x[j] = outs[r * 257 + lane + 64 * j];
            s += x[j]; q += x[j] * x[j];
        }
        #pragma unroll
        for (int off = 1; off < 64; off <<= 1) {
            s += __shfl_xor(s, off);
            q += __shfl_xor(q, off);
        }
        float mn = s * (1.f / 256.f);
        float inv = rsqrtf(q * (1.f / 256.f) - mn * mn + LN_EPS);
        #pragma unroll
        for (int j = 0; j < 4; ++j) {
            int c = lane + 64 * j;
            float nv = (x[j] - mn) * inv * gs[c] + gb[c];
            if (resid) nv += hs[r * 256 + c];
            hs[r * 256 + c] = nv;
            hs_b[r * 264 + c] = f2bf(nv);
        }
    }
}

__global__ __launch_bounds__(512) void k_xformer(
    const float* __restrict__ pooled, const float* __restrict__ padf,
    const unsigned short* __restrict__ wpk,
    const float* __restrict__ pb, const float* __restrict__ lps, const float* __restrict__ lpb,
    const float* __restrict__ qkvb, const float* __restrict__ obv,
    const float* __restrict__ las, const float* __restrict__ lab,
    const float* __restrict__ lms, const float* __restrict__ lmb,
    const float* __restrict__ hw, const float* __restrict__ hb,
    float* __restrict__ out)
{
    __shared__ __align__(16) char smem[124032];
    float* hs = (float*)(smem);
    unsigned short* hs_b = (unsigned short*)(smem + 32768);
    unsigned short* R1 = (unsigned short*)(smem + 49664);
    unsigned short* q_s = R1;                   // per-head stride 2304 elems
    unsigned short* k_s = R1 + 9216;
    unsigned short* us_b = R1;                  // [32][520]
    unsigned short* v_cm = (unsigned short*)(smem + 86528);    // [4][64][40], head stride 2560
    unsigned short* ys_b = (unsigned short*)(smem + 107008);   // [32][264]
    float* outs = (float*)(smem + 86528);       // [32][257]
    unsigned short* pool_b = (unsigned short*)(smem + 86528);  // [32][72]
    float* padc = (float*)(smem + 123904);

    const int b = blockIdx.x, t = threadIdx.x;
    const int w = t >> 6, lane = t & 63, lo = lane & 15, kg = lane >> 4;

    // ---- P0: load pad flags + pooled (mean) ----
    if (t < 32) padc[t] = padf[b * 32 + t];
    for (int i = t; i < 2048; i += 512) {
        int r = i >> 6, k = i & 63;
        pool_b[r * 72 + k] = f2bf(pooled[((size_t)b * 32 + r) * 64 + k] * (1.f / 7056.f));
    }
    __syncthreads();

    // ---- P1: proj (64->256) + bias + LN -> hs ----
    {
        fx4 acc[1][4];
        #pragma unroll
        for (int n = 0; n < 4; ++n) acc[0][n] = (fx4){0.f, 0.f, 0.f, 0.f};
        int m0 = w & 1, nt0 = (w >> 1) * 4;
        mfma_gemm<1, 4, 2>(pool_b, 72, m0, wpk + 1048576, 64, nt0, acc, lane);
        __syncthreads();   // pool_b dead; outs aliases it
        #pragma unroll
        for (int n = 0; n < 4; ++n) {
            int c = (nt0 + n) * 16 + lo;
            float bias = pb[c];
            #pragma unroll
            for (int rg = 0; rg < 4; ++rg)
                outs[(m0 * 16 + kg * 4 + rg) * 257 + c] = acc[0][n][rg] + bias;
        }
        __syncthreads();
        ln_update(outs, hs, hs_b, lps, lpb, false, w, lane);
        __syncthreads();
    }

    // ---- transformer layers ----
    for (int l = 0; l < 2; ++l) {
        const unsigned short* wq = wpk + (size_t)l * 196608;
        const unsigned short* wo = wpk + 393216 + (size_t)l * 65536;
        const unsigned short* wu = wpk + 524288 + (size_t)l * 131072;
        const unsigned short* wd = wpk + 786432 + (size_t)l * 131072;

        // qkv (256 -> 768) + bias + RoPE -> q_s, k_s, v_cm
        {
            fx4 acc[2][6];
            #pragma unroll
            for (int m = 0; m < 2; ++m)
                #pragma unroll
                for (int n = 0; n < 6; ++n) acc[m][n] = (fx4){0.f, 0.f, 0.f, 0.f};
            int nt0 = w * 6;
            mfma_gemm<2, 6, 8>(hs_b, 264, 0, wq, 256, nt0, acc, lane);
            #pragma unroll
            for (int n = 0; n < 6; ++n) {
                int c = (nt0 + n) * 16 + lo;
                int kind = c >> 8, cl = c & 255, h = cl >> 6, d = cl & 63;
                float bias = qkvb[l * 768 + c];
                if (kind < 2) {
                    int j = d >> 1;
                    float freq = exp2f(-(float)j * 0.41524101186f);
                    unsigned short* dst = (kind ? k_s : q_s) + h * 2304;
                    #pragma unroll
                    for (int m = 0; m < 2; ++m)
                        #pragma unroll
                        for (int rg = 0; rg < 4; ++rg) {
                            float val = acc[m][n][rg] + bias;
                            float prt = __shfl_xor(val, 1);
                            int r = m * 16 + kg * 4 + rg;
                            float sn, cs;
                            __sincosf((float)r * freq, &sn, &cs);
                            float rv = (d & 1) ? (val * cs + prt * sn) : (val * cs - prt * sn);
                            dst[r * 72 + d] = f2bf(rv);
                        }
                } else {
                    #pragma unroll
                    for (int m = 0; m < 2; ++m)
                        #pragma unroll
                        for (int rg = 0; rg < 4; ++rg) {
                            int r = m * 16 + kg * 4 + rg;
                            v_cm[(h * 64 + d) * 40 + r] = f2bf(acc[m][n][rg] + bias);
                        }
                }
            }
            __syncthreads();
        }

        // scores = QK^T * scale, mask, softmax -> pa (aliases q_s)
        {
            int h = w >> 1, mt = w & 1;
            fx4 sc[1][2];
            sc[0][0] = (fx4){0.f, 0.f, 0.f, 0.f};
            sc[0][1] = (fx4){0.f, 0.f, 0.f, 0.f};
            mfma_gemm<1, 2, 2>(q_s + h * 2304, 72, mt, k_s + h * 2304, 72, 0, sc, lane);
            __syncthreads();    // all q_s reads done before pa overwrites
            unsigned short* pa = R1 + h * 2304;   // [32][40]
            float pad0 = padc[lo], pad1 = padc[16 + lo];
            #pragma unroll
            for (int rg = 0; rg < 4; ++rg) {
                int qr = mt * 16 + kg * 4 + rg;
                float v0 = (lo <= qr && pad0 != 0.f) ? sc[0][0][rg] * 0.125f : -1e9f;
                float v1 = ((16 + lo) <= qr && pad1 != 0.f) ? sc[0][1][rg] * 0.125f : -1e9f;
                float mx = fmaxf(v0, v1);
                #pragma unroll
                for (int off = 1; off < 16; off <<= 1) mx = fmaxf(mx, __shfl_xor(mx, off));
                float e0 = __expf(v0 - mx), e1 = __expf(v1 - mx);
                float sm = e0 + e1;
                #pragma unroll
                for (int off = 1; off < 16; off <<= 1) sm += __shfl_xor(sm, off);
                float inv = 1.f / sm;
                pa[qr * 40 + lo] = f2bf(e0 * inv);
                pa[qr * 40 + 16 + lo] = f2bf(e1 * inv);
            }
            __syncthreads();
        }

        // y = P @ V -> ys_b
        {
            int h = w >> 1, mt = w & 1;
            fx4 yv[1][4];
            #pragma unroll
            for (int n = 0; n < 4; ++n) yv[0][n] = (fx4){0.f, 0.f, 0.f, 0.f};
            mfma_gemm<1, 4, 1>(R1 + h * 2304, 40, mt, v_cm + h * 2560, 40, 0, yv, lane);
            #pragma unroll
            for (int n = 0; n < 4; ++n) {
                int d = n * 16 + lo;
                #pragma unroll
                for (int rg = 0; rg < 4; ++rg)
                    ys_b[(mt * 16 + kg * 4 + rg) * 264 + h * 64 + d] = f2bf(yv[0][n][rg]);
            }
            __syncthreads();
        }

        // out-proj (256->256) + bias + pad-mask -> outs; LN + residual -> hs
        {
            fx4 ac[2][2];
            #pragma unroll
            for (int m = 0; m < 2; ++m) { ac[m][0] = (fx4){0.f,0.f,0.f,0.f}; ac[m][1] = (fx4){0.f,0.f,0.f,0.f}; }
            mfma_gemm<2, 2, 8>(ys_b, 264, 0, wo, 256, w * 2, ac, lane);
            __syncthreads();   // ys_b/v_cm dead; outs aliases them
            #pragma unroll
            for (int n = 0; n < 2; ++n) {
                int c = (w * 2 + n) * 16 + lo;
                float bias = obv[l * 256 + c];
                #pragma unroll
                for (int m = 0; m < 2; ++m)
                    #pragma unroll
                    for (int rg = 0; rg < 4; ++rg) {
                        int r = m * 16 + kg * 4 + rg;
                        outs[r * 257 + c] = (ac[m][n][rg] + bias) * padc[r];
                    }
            }
            __syncthreads();
            ln_update(outs, hs, hs_b, las + l * 256, lab + l * 256, true, w, lane);
            __syncthreads();
        }

        // mlp up (256->512) + ReLU -> us_b
        {
            fx4 au[2][4];
            #pragma unroll
            for (int m = 0; m < 2; ++m)
                #pragma unroll
                for (int n = 0; n < 4; ++n) au[m][n] = (fx4){0.f, 0.f, 0.f, 0.f};
            mfma_gemm<2, 4, 8>(hs_b, 264, 0, wu, 256, w * 4, au, lane);
            #pragma unroll
            for (int n = 0; n < 4; ++n) {
                int c = (w * 4 + n) * 16 + lo;
                #pragma unroll
                for (int m = 0; m < 2; ++m)
                    #pragma unroll
                    for (int rg = 0; rg < 4; ++rg)
                        us_b[(m * 16 + kg * 4 + rg) * 520 + c] = f2bf(fmaxf(au[m][n][rg], 0.f));
            }
            __syncthreads();
        }

        // mlp down (512->256) -> outs; LN + residual -> hs
        {
            fx4 ad[2][2];
            #pragma unroll
            for (int m = 0; m < 2; ++m) { ad[m][0] = (fx4){0.f,0.f,0.f,0.f}; ad[m][1] = (fx4){0.f,0.f,0.f,0.f}; }
            mfma_gemm<2, 2, 16>(us_b, 520, 0, wd, 512, w * 2, ad, lane);
            #pragma unroll
            for (int n = 0; n < 2; ++n) {
                int c = (w * 2 + n) * 16 + lo;
                #pragma unroll
                for (int m = 0; m < 2; ++m)
                    #pragma unroll
                    for (int rg = 0; rg < 4; ++rg)
                        outs[(m * 16 + kg * 4 + rg) * 257 + c] = ad[m][n][rg];
            }
            __syncthreads();
            ln_update(outs, hs, hs_b, lms + l * 256, lmb + l * 256, true, w, lane);
            __syncthreads();
        }
    }

    // ---- head (256->18) ----
    for (int idx = t; idx < 576; idx += 512) {
        int r = idx / 18, a = idx - r * 18;
        float acch = hb[a];
        #pragma unroll 8
        for (int k = 0; k < 256; ++k) acch = fmaf(hs[r * 256 + k], hw[k * 18 + a], acch);
        out[((size_t)b * 32 + r) * 18 + a] = acch;
    }
}

extern "C" void kernel_launch(void* const* d_in, const int* in_sizes, int n_in,
                              void* d_out, int out_size, void* d_ws, size_t ws_size,
                              hipStream_t stream)
{
    (void)in_sizes; (void)n_in; (void)out_size; (void)ws_size;
    const float* x   = (const float*)d_in[0];
    const unsigned char* pad = (const unsigned char*)d_in[1];
    const float* c0w = (const float*)d_in[2];
    const float* c0b = (const float*)d_in[3];
    const float* l0s = (const float*)d_in[4];
    const float* l0b = (const float*)d_in[5];
    const float* c1w = (const float*)d_in[6];
    const float* c1b = (const float*)d_in[7];
    const float* l1s = (const float*)d_in[8];
    const float* l1b = (const float*)d_in[9];
    const float* pw  = (const float*)d_in[10];
    const float* pb  = (const float*)d_in[11];
    const float* lps = (const float*)d_in[12];
    const float* lpb = (const float*)d_in[13];
    const float* qkvw = (const float*)d_in[14];
    const float* qkvb = (const float*)d_in[15];
    const float* ow  = (const float*)d_in[16];
    const float* obv = (const float*)d_in[17];
    const float* las = (const float*)d_in[18];
    const float* lab = (const float*)d_in[19];
    const float* upw = (const float*)d_in[20];
    const float* dww = (const float*)d_in[21];
    const float* lms = (const float*)d_in[22];
    const float* lmb = (const float*)d_in[23];
    const float* hw  = (const float*)d_in[24];
    const float* hb  = (const float*)d_in[25];
    float* out = (float*)d_out;

    char* ws = (char*)d_ws;
    size_t off = 0;
    auto alloc = [&](size_t bytes) -> void* {
        void* p = ws + off;
        off = (off + bytes + 255) & ~(size_t)255;
        return p;
    };
    unsigned short* wtb = (unsigned short*)alloc(20480 * 2);
    unsigned short* wpk = (unsigned short*)alloc((size_t)1064960 * 2);
    float* pooled = (float*)alloc(512 * 64 * 4);
    float* padf   = (float*)alloc(512 * 4);

    hipMemsetAsync(pooled, 0, 512 * 64 * 4, stream);
    k_pad<<<1, 512, 0, stream>>>(pad, padf);
    k_wprep<<<80, 256, 0, stream>>>(c1w, c0w, wtb);
    k_wpack<<<4160, 256, 0, stream>>>(qkvw, ow, upw, dww, pw, wpk);
    k_conv1<<<14336, 256, 0, stream>>>(x, wtb, c0b, l0s, l0b, c1b, l1s, l1b, pooled);
    k_xformer<<<16, 512, 0, stream>>>(pooled, padf, wpk, pb, lps, lpb,
                                      qkvb, obv, las, lab, lms, lmb, hw, hb, out);
}

// Round 6
// 435.912 us; speedup vs baseline: 2.2685x; 1.2269x over previous
//
#include <hip/hip_runtime.h>
#include <hip/hip_bf16.h>

#define LN_EPS 1e-6f

typedef __attribute__((ext_vector_type(8))) short bf16x8;
typedef __attribute__((ext_vector_type(4))) float fx4;

struct U8 { union { bf16x8 v; uint2 p[2]; }; };

__device__ __forceinline__ unsigned short f2bf(float f) {
    union { __hip_bfloat16 b; unsigned short u; } cv;
    cv.b = __float2bfloat16(f);
    return cv.u;
}

// ---------- pad dtype detector: u8 bool vs int32 ----------
__global__ void k_pad(const unsigned char* __restrict__ p, float* __restrict__ padf) {
    __shared__ int cnt;
    int t = threadIdx.x;                  // 512 threads
    if (t == 0) cnt = 0;
    __syncthreads();
    if (p[t]) atomicAdd(&cnt, 1);
    __syncthreads();
    float v;
    if (cnt > 256) v = p[t] ? 1.f : 0.f;                       // u8 bools
    else           v = ((const int*)p)[t] ? 1.f : 0.f;          // int32 per elem
    padf[t] = v;
}

// ---------- weight repack ----------
// wtb[0..18432): conv1 (3,3,32,64) -> [tap][co][kg][j] bf16
// wtb[18432..20480): conv0 (3,3,4,32) -> wc0[ch 32][k 64] bf16, k=(tap<<2)|ci, zero-padded k>=36
__global__ void k_wprep(const float* __restrict__ w1, const float* __restrict__ w0,
                        unsigned short* __restrict__ wtb) {
    int idx = blockIdx.x * 256 + threadIdx.x;   // 20480 exactly
    if (idx < 18432) {
        int j  = idx & 7;
        int kg = (idx >> 3) & 3;
        int co = (idx >> 5) & 63;
        int tp = idx >> 11;
        wtb[idx] = f2bf(w1[((size_t)tp * 32 + kg * 8 + j) * 64 + co]);
    } else {
        int r = idx - 18432;
        int ch = r >> 6, k = r & 63;
        float v = 0.f;
        if (k < 36) v = w0[(size_t)k * 32 + ch];   // (tap*4+ci)*32+ch == k*32+ch
        wtb[idx] = f2bf(v);
    }
}

// ---------- tail weight pack: all transformer weights -> bf16 col-major [N][K] ----------
// layout in wpk (elems): qkv 2*768*256 | out 2*256*256 | up 2*512*256 | down 2*256*512 | proj 256*64
__global__ void k_wpack(const float* __restrict__ qkvw, const float* __restrict__ ow,
                        const float* __restrict__ upw, const float* __restrict__ dww,
                        const float* __restrict__ pw, unsigned short* __restrict__ wpk)
{
    int idx = blockIdx.x * 256 + threadIdx.x;
    if (idx >= 1064960) return;
    float v;
    if (idx < 393216) {
        int l = idx / 196608, rm = idx % 196608, n = rm >> 8, k = rm & 255;
        v = qkvw[((size_t)l * 256 + k) * 768 + n];
    } else if (idx < 524288) {
        int r = idx - 393216, l = r >> 16, rm = r & 65535, n = rm >> 8, k = rm & 255;
        v = ow[((size_t)l * 256 + k) * 256 + n];
    } else if (idx < 786432) {
        int r = idx - 524288, l = r >> 17, rm = r & 131071, n = rm >> 8, k = rm & 255;
        v = upw[((size_t)l * 256 + k) * 512 + n];
    } else if (idx < 1048576) {
        int r = idx - 786432, l = r >> 17, rm = r & 131071, n = rm >> 9, k = rm & 511;
        v = dww[((size_t)l * 512 + k) * 256 + n];
    } else {
        int r = idx - 1048576, n = r >> 6, k = r & 63;
        v = pw[k * 256 + n];
    }
    wpk[idx] = f2bf(v);
}

// ---------- fused conv0+conv1 + LN + ReLU + mean-pool ----------
// Block: one image x 3 output rows.
// Phase 0: stage x rows y0-2..y0+4 as bf16 -> xs[7][86][4] (zero-padded halo).
// Phase 1 (operand-swapped): conv0 = MFMA(A=wc0[32ch][64k], B=pixels). Lane owns
//   pixel np*16+lo and 8 channels (m*16+kg*4+rg); LN(32) stats = 4 shfl (off 16/32);
//   write = 2 conflict-free ds_write_b64 of packed bf16.
// Phase 2: conv1 implicit GEMM (unchanged) + bias + LN(64) + ReLU + pool.
__global__ __launch_bounds__(256, 3) void k_conv1(
    const float* __restrict__ x, const unsigned short* __restrict__ wtb,
    const float* __restrict__ c0b, const float* __restrict__ l0s, const float* __restrict__ l0b,
    const float* __restrict__ bias, const float* __restrict__ lns, const float* __restrict__ lnb,
    float* __restrict__ pooled)
{
    __shared__ __align__(16) unsigned short At[4][5][86][8];   // 27520 B
    __shared__ __align__(16) unsigned short xs[7][86][4];      // 4816 B
    __shared__ float pool_w[4][64];
    const int tid = threadIdx.x;
    const int img = blockIdx.x / 28;
    const int rg  = blockIdx.x - img * 28;
    const int y0  = rg * 3;

    const int lane = tid & 63;
    const int wv = tid >> 6;
    const int lo = lane & 15;
    const int kg = lane >> 4;

    // ---- phase 0: stage x (7 rows, bf16, halo-padded) + zero At/xs halo cols ----
    if (tid >= 64 && tid < 104) {
        int z = tid - 64;
        int zk = z / 10, rem = z - zk * 10, zr = rem >> 1, side = rem & 1;
        *reinterpret_cast<uint4*>(&At[zk][zr][side ? 85 : 0][0]) = (uint4){0, 0, 0, 0};
    }
    if (tid >= 104 && tid < 118) {
        int z = tid - 104, row = z >> 1, side = z & 1;
        *reinterpret_cast<uint2*>(&xs[row][side ? 85 : 0][0]) = (uint2){0, 0};
    }
    for (int i = tid; i < 588; i += 256) {
        int row = i / 84, c = i - row * 84;
        int gy = y0 - 2 + row;
        float4 v = (float4){0.f, 0.f, 0.f, 0.f};
        if (gy >= 0 && gy < 84)
            v = *reinterpret_cast<const float4*>(x + ((size_t)img * 7056 + gy * 84 + c) * 4);
        unsigned l32 = (unsigned)f2bf(v.x) | ((unsigned)f2bf(v.y) << 16);
        unsigned h32 = (unsigned)f2bf(v.z) | ((unsigned)f2bf(v.w) << 16);
        *reinterpret_cast<uint2*>(&xs[row][c + 1][0]) = (uint2){l32, h32};
    }
    __syncthreads();

    // ---- phase 1: conv0 via MFMA (operand-swapped) -> At ----
    {
        const unsigned short* wc0 = wtb + 18432;
        // A-frags: weight rows m*16+lo, k-granule kg; block0 (k 0..31), block1 (k 32..63)
        bf16x8 W0[2], W1[2];
        #pragma unroll
        for (int m = 0; m < 2; ++m) {
            W0[m] = *reinterpret_cast<const bf16x8*>(wc0 + (m * 16 + lo) * 64 + kg * 8);
            W1[m] = *reinterpret_cast<const bf16x8*>(wc0 + (m * 16 + lo) * 64 + 32 + kg * 8);
        }
        // LN params for this lane's 8 channels: ch = m*16 + kg*4 + rg
        float cb[2][4], sg[2][4], bg[2][4];
        #pragma unroll
        for (int m = 0; m < 2; ++m)
            #pragma unroll
            for (int r = 0; r < 4; ++r) {
                int c = m * 16 + kg * 4 + r;
                cb[m][r] = c0b[c]; sg[m][r] = l0s[c]; bg[m][r] = l0b[c];
            }
        const int t0 = 2 * kg, t1 = 2 * kg + 1;
        const int dy0 = t0 / 3, dx0 = t0 % 3, dy1 = t1 / 3, dx1 = t1 % 3;
        const unsigned short* xsb = &xs[0][0][0];

        for (int it = 0; it < 7; ++it) {
            int np = it * 4 + wv;
            if (np >= 27) break;
            int px = np * 16 + lo;
            int pxc = px < 420 ? px : 419;
            int r5 = pxc / 84, col = pxc - r5 * 84;
            // B-frag: pixel px, k-granule kg
            U8 a0u, a1u;
            a0u.p[0] = *reinterpret_cast<const uint2*>(xsb + ((r5 + dy0) * 86 + col + dx0) * 4);
            a0u.p[1] = *reinterpret_cast<const uint2*>(xsb + ((r5 + dy1) * 86 + col + dx1) * 4);
            if (kg == 0)
                a1u.p[0] = *reinterpret_cast<const uint2*>(xsb + ((r5 + 2) * 86 + col + 2) * 4);
            else
                a1u.p[0] = (uint2){0, 0};
            a1u.p[1] = (uint2){0, 0};

            fx4 c2[2];
            c2[0] = (fx4){0.f, 0.f, 0.f, 0.f};
            c2[1] = (fx4){0.f, 0.f, 0.f, 0.f};
            c2[0] = __builtin_amdgcn_mfma_f32_16x16x32_bf16(W0[0], a0u.v, c2[0], 0, 0, 0);
            c2[0] = __builtin_amdgcn_mfma_f32_16x16x32_bf16(W1[0], a1u.v, c2[0], 0, 0, 0);
            c2[1] = __builtin_amdgcn_mfma_f32_16x16x32_bf16(W0[1], a0u.v, c2[1], 0, 0, 0);
            c2[1] = __builtin_amdgcn_mfma_f32_16x16x32_bf16(W1[1], a1u.v, c2[1], 0, 0, 0);

            // lane holds ch m*16+kg*4+rg of pixel px
            float v[2][4], s = 0.f, q = 0.f;
            #pragma unroll
            for (int m = 0; m < 2; ++m)
                #pragma unroll
                for (int r = 0; r < 4; ++r) {
                    v[m][r] = c2[m][r] + cb[m][r];
                    s += v[m][r]; q += v[m][r] * v[m][r];
                }
            s += __shfl_xor(s, 16); q += __shfl_xor(q, 16);
            s += __shfl_xor(s, 32); q += __shfl_xor(q, 32);
            float mn = s * (1.f / 32.f);
            float inv = rsqrtf(q * (1.f / 32.f) - mn * mn + LN_EPS);

            if (px < 420) {
                int yA = y0 - 1 + r5;
                bool gv = (unsigned)yA < 84u;
                #pragma unroll
                for (int m = 0; m < 2; ++m) {
                    uint2 pk = (uint2){0, 0};
                    if (gv) {
                        unsigned short o0 = f2bf(fmaxf((v[m][0] - mn) * inv * sg[m][0] + bg[m][0], 0.f));
                        unsigned short o1 = f2bf(fmaxf((v[m][1] - mn) * inv * sg[m][1] + bg[m][1], 0.f));
                        unsigned short o2 = f2bf(fmaxf((v[m][2] - mn) * inv * sg[m][2] + bg[m][2], 0.f));
                        unsigned short o3 = f2bf(fmaxf((v[m][3] - mn) * inv * sg[m][3] + bg[m][3], 0.f));
                        pk.x = (unsigned)o0 | ((unsigned)o1 << 16);
                        pk.y = (unsigned)o2 | ((unsigned)o3 << 16);
                    }
                    // granule = 2m + (kg>>1), elem offset (kg&1)*4 -> 8B-aligned b64 write
                    *reinterpret_cast<uint2*>(&At[2 * m + (kg >> 1)][r5][col + 1][(kg & 1) * 4]) = pk;
                }
            }
        }
    }
    __syncthreads();

    // ---- phase 2: conv1 implicit GEMM (unchanged) ----
    int abase[4];
    #pragma unroll
    for (int m = 0; m < 4; ++m) {
        int pl = wv * 64 + m * 16 + lo;
        if (pl > 251) pl = 251;
        int rl = pl / 84;
        int c = pl - rl * 84;
        abase[m] = ((kg * 5 + rl) * 86 + c) * 8;
    }

    fx4 acc[4][4];
    #pragma unroll
    for (int m = 0; m < 4; ++m)
        #pragma unroll
        for (int n = 0; n < 4; ++n) acc[m][n] = (fx4){0.f, 0.f, 0.f, 0.f};

    const unsigned short* Abase = &At[0][0][0][0];
    #pragma unroll
    for (int dy = 0; dy < 3; ++dy) {
        #pragma unroll
        for (int dx = 0; dx < 3; ++dx) {
            const int t = dy * 3 + dx;
            bf16x8 Bf[4];
            #pragma unroll
            for (int n = 0; n < 4; ++n)
                Bf[n] = *reinterpret_cast<const bf16x8*>(
                    wtb + (size_t)((t * 64 + n * 16 + lo) * 4 + kg) * 8);
            #pragma unroll
            for (int m = 0; m < 4; ++m) {
                bf16x8 Af = *reinterpret_cast<const bf16x8*>(Abase + abase[m] + (dy * 86 + dx) * 8);
                #pragma unroll
                for (int n = 0; n < 4; ++n)
                    acc[m][n] = __builtin_amdgcn_mfma_f32_16x16x32_bf16(Af, Bf[n], acc[m][n], 0, 0, 0);
            }
        }
    }

    // ---- phase 3: bias + LN(64) + ReLU + pool ----
    float bs[4], ss[4], bb[4];
    #pragma unroll
    for (int n = 0; n < 4; ++n) {
        int c = n * 16 + lo;
        bs[n] = bias[c]; ss[n] = lns[c]; bb[n] = lnb[c];
    }
    float pv[4] = {0.f, 0.f, 0.f, 0.f};
    #pragma unroll
    for (int m = 0; m < 4; ++m) {
        #pragma unroll
        for (int r = 0; r < 4; ++r) {
            float v0 = acc[m][0][r] + bs[0], v1 = acc[m][1][r] + bs[1];
            float v2 = acc[m][2][r] + bs[2], v3 = acc[m][3][r] + bs[3];
            float s = v0 + v1 + v2 + v3;
            float q = v0 * v0 + v1 * v1 + v2 * v2 + v3 * v3;
            #pragma unroll
            for (int off = 1; off < 16; off <<= 1) {
                s += __shfl_xor(s, off);
                q += __shfl_xor(q, off);
            }
            float mn = s * (1.f / 64.f);
            float var = q * (1.f / 64.f) - mn * mn;
            float inv = rsqrtf(var + LN_EPS);
            int pix = wv * 64 + m * 16 + kg * 4 + r;
            float valid = (pix < 252) ? 1.f : 0.f;
            pv[0] += fmaxf((v0 - mn) * inv * ss[0] + bb[0], 0.f) * valid;
            pv[1] += fmaxf((v1 - mn) * inv * ss[1] + bb[1], 0.f) * valid;
            pv[2] += fmaxf((v2 - mn) * inv * ss[2] + bb[2], 0.f) * valid;
            pv[3] += fmaxf((v3 - mn) * inv * ss[3] + bb[3], 0.f) * valid;
        }
    }
    #pragma unroll
    for (int n = 0; n < 4; ++n) {
        float v = pv[n];
        v += __shfl_xor(v, 16);
        v += __shfl_xor(v, 32);
        if (lane < 16) pool_w[wv][n * 16 + lane] = v;
    }
    __syncthreads();
    if (tid < 64) {
        float s = pool_w[0][tid] + pool_w[1][tid] + pool_w[2][tid] + pool_w[3][tid];
        atomicAdd(&pooled[img * 64 + tid], s);
    }
}

// ================= fused per-batch transformer =================
template<int MT, int NT, int KS>
__device__ __forceinline__ void mfma_gemm(
    const unsigned short* A, int lda, int m0,
    const unsigned short* B, int ldb, int nt0,
    fx4 (&acc)[MT][NT], int lane)
{
    const int lo = lane & 15, kg = lane >> 4;
    #pragma unroll
    for (int ks = 0; ks < KS; ++ks) {
        const int k = ks * 32 + kg * 8;
        bf16x8 af[MT];
        #pragma unroll
        for (int m = 0; m < MT; ++m)
            af[m] = *reinterpret_cast<const bf16x8*>(A + (size_t)((m0 + m) * 16 + lo) * lda + k);
        #pragma unroll
        for (int n = 0; n < NT; ++n) {
            bf16x8 bf = *reinterpret_cast<const bf16x8*>(B + (size_t)((nt0 + n) * 16 + lo) * ldb + k);
            #pragma unroll
            for (int m = 0; m < MT; ++m)
                acc[m][n] = __builtin_amdgcn_mfma_f32_16x16x32_bf16(af[m], bf, acc[m][n], 0, 0, 0);
        }
    }
}

__device__ __forceinline__ void ln_update(
    const float* outs /*[32][257] LDS*/, float* hs, unsigned short* hs_b,
    const float* gs, const float* gb, bool resid, int w, int lane)
{
    #pragma unroll
    for (int i = 0; i < 4; ++i) {
        int r = w * 4 + i;
        float x[4], s = 0.f, q = 0.f;
        #pragma unroll
        for (int j = 0; j < 4; ++j) {
            x[j] = outs[r * 257 + lane + 64 * j];
            s += x[j]; q += x[j] * x[j];
        }
        #pragma unroll
        for (int off = 1; off < 64; off <<= 1) {
            s += __shfl_xor(s, off);
            q += __shfl_xor(q, off);
        }
        float mn = s * (1.f / 256.f);
        float inv = rsqrtf(q * (1.f / 256.f) - mn * mn + LN_EPS);
        #pragma unroll
        for (int j = 0; j < 4; ++j) {
            int c = lane + 64 * j;
            float nv = (x[j] - mn) * inv * gs[c] + gb[c];
            if (resid) nv += hs[r * 256 + c];
            hs[r * 256 + c] = nv;
            hs_b[r * 264 + c] = f2bf(nv);
        }
    }
}

__global__ __launch_bounds__(512) void k_xformer(
    const float* __restrict__ pooled, const float* __restrict__ padf,
    const unsigned short* __restrict__ wpk,
    const float* __restrict__ pb, const float* __restrict__ lps, const float* __restrict__ lpb,
    const float* __restrict__ qkvb, const float* __restrict__ obv,
    const float* __restrict__ las, const float* __restrict__ lab,
    const float* __restrict__ lms, const float* __restrict__ lmb,
    const float* __restrict__ hw, const float* __restrict__ hb,
    float* __restrict__ out)
{
    __shared__ __align__(16) char smem[124032];
    float* hs = (float*)(smem);
    unsigned short* hs_b = (unsigned short*)(smem + 32768);
    unsigned short* R1 = (unsigned short*)(smem + 49664);
    unsigned short* q_s = R1;                   // per-head stride 2304 elems
    unsigned short* k_s = R1 + 9216;
    unsigned short* us_b = R1;                  // [32][520]
    unsigned short* v_cm = (unsigned short*)(smem + 86528);    // [4][64][40], head stride 2560
    unsigned short* ys_b = (unsigned short*)(smem + 107008);   // [32][264]
    float* outs = (float*)(smem + 86528);       // [32][257]
    unsigned short* pool_b = (unsigned short*)(smem + 86528);  // [32][72]
    float* padc = (float*)(smem + 123904);

    const int b = blockIdx.x, t = threadIdx.x;
    const int w = t >> 6, lane = t & 63, lo = lane & 15, kg = lane >> 4;

    // ---- P0: load pad flags + pooled (mean) ----
    if (t < 32) padc[t] = padf[b * 32 + t];
    for (int i = t; i < 2048; i += 512) {
        int r = i >> 6, k = i & 63;
        pool_b[r * 72 + k] = f2bf(pooled[((size_t)b * 32 + r) * 64 + k] * (1.f / 7056.f));
    }
    __syncthreads();

    // ---- P1: proj (64->256) + bias + LN -> hs ----
    {
        fx4 acc[1][4];
        #pragma unroll
        for (int n = 0; n < 4; ++n) acc[0][n] = (fx4){0.f, 0.f, 0.f, 0.f};
        int m0 = w & 1, nt0 = (w >> 1) * 4;
        mfma_gemm<1, 4, 2>(pool_b, 72, m0, wpk + 1048576, 64, nt0, acc, lane);
        __syncthreads();   // pool_b dead; outs aliases it
        #pragma unroll
        for (int n = 0; n < 4; ++n) {
            int c = (nt0 + n) * 16 + lo;
            float bias = pb[c];
            #pragma unroll
            for (int rg = 0; rg < 4; ++rg)
                outs[(m0 * 16 + kg * 4 + rg) * 257 + c] = acc[0][n][rg] + bias;
        }
        __syncthreads();
        ln_update(outs, hs, hs_b, lps, lpb, false, w, lane);
        __syncthreads();
    }

    // ---- transformer layers ----
    for (int l = 0; l < 2; ++l) {
        const unsigned short* wq = wpk + (size_t)l * 196608;
        const unsigned short* wo = wpk + 393216 + (size_t)l * 65536;
        const unsigned short* wu = wpk + 524288 + (size_t)l * 131072;
        const unsigned short* wd = wpk + 786432 + (size_t)l * 131072;

        // qkv (256 -> 768) + bias + RoPE -> q_s, k_s, v_cm
        {
            fx4 acc[2][6];
            #pragma unroll
            for (int m = 0; m < 2; ++m)
                #pragma unroll
                for (int n = 0; n < 6; ++n) acc[m][n] = (fx4){0.f, 0.f, 0.f, 0.f};
            int nt0 = w * 6;
            mfma_gemm<2, 6, 8>(hs_b, 264, 0, wq, 256, nt0, acc, lane);
            #pragma unroll
            for (int n = 0; n < 6; ++n) {
                int c = (nt0 + n) * 16 + lo;
                int kind = c >> 8, cl = c & 255, h = cl >> 6, d = cl & 63;
                float bias = qkvb[l * 768 + c];
                if (kind < 2) {
                    int j = d >> 1;
                    float freq = exp2f(-(float)j * 0.41524101186f);
                    unsigned short* dst = (kind ? k_s : q_s) + h * 2304;
                    #pragma unroll
                    for (int m = 0; m < 2; ++m)
                        #pragma unroll
                        for (int rg = 0; rg < 4; ++rg) {
                            float val = acc[m][n][rg] + bias;
                            float prt = __shfl_xor(val, 1);
                            int r = m * 16 + kg * 4 + rg;
                            float sn, cs;
                            __sincosf((float)r * freq, &sn, &cs);
                            float rv = (d & 1) ? (val * cs + prt * sn) : (val * cs - prt * sn);
                            dst[r * 72 + d] = f2bf(rv);
                        }
                } else {
                    #pragma unroll
                    for (int m = 0; m < 2; ++m)
                        #pragma unroll
                        for (int rg = 0; rg < 4; ++rg) {
                            int r = m * 16 + kg * 4 + rg;
                            v_cm[(h * 64 + d) * 40 + r] = f2bf(acc[m][n][rg] + bias);
                        }
                }
            }
            __syncthreads();
        }

        // scores = QK^T * scale, mask, softmax -> pa (aliases q_s)
        {
            int h = w >> 1, mt = w & 1;
            fx4 sc[1][2];
            sc[0][0] = (fx4){0.f, 0.f, 0.f, 0.f};
            sc[0][1] = (fx4){0.f, 0.f, 0.f, 0.f};
            mfma_gemm<1, 2, 2>(q_s + h * 2304, 72, mt, k_s + h * 2304, 72, 0, sc, lane);
            __syncthreads();    // all q_s reads done before pa overwrites
            unsigned short* pa = R1 + h * 2304;   // [32][40]
            float pad0 = padc[lo], pad1 = padc[16 + lo];
            #pragma unroll
            for (int rg = 0; rg < 4; ++rg) {
                int qr = mt * 16 + kg * 4 + rg;
                float v0 = (lo <= qr && pad0 != 0.f) ? sc[0][0][rg] * 0.125f : -1e9f;
                float v1 = ((16 + lo) <= qr && pad1 != 0.f) ? sc[0][1][rg] * 0.125f : -1e9f;
                float mx = fmaxf(v0, v1);
                #pragma unroll
                for (int off = 1; off < 16; off <<= 1) mx = fmaxf(mx, __shfl_xor(mx, off));
                float e0 = __expf(v0 - mx), e1 = __expf(v1 - mx);
                float sm = e0 + e1;
                #pragma unroll
                for (int off = 1; off < 16; off <<= 1) sm += __shfl_xor(sm, off);
                float inv = 1.f / sm;
                pa[qr * 40 + lo] = f2bf(e0 * inv);
                pa[qr * 40 + 16 + lo] = f2bf(e1 * inv);
            }
            __syncthreads();
        }

        // y = P @ V -> ys_b
        {
            int h = w >> 1, mt = w & 1;
            fx4 yv[1][4];
            #pragma unroll
            for (int n = 0; n < 4; ++n) yv[0][n] = (fx4){0.f, 0.f, 0.f, 0.f};
            mfma_gemm<1, 4, 1>(R1 + h * 2304, 40, mt, v_cm + h * 2560, 40, 0, yv, lane);
            #pragma unroll
            for (int n = 0; n < 4; ++n) {
                int d = n * 16 + lo;
                #pragma unroll
                for (int rg = 0; rg < 4; ++rg)
                    ys_b[(mt * 16 + kg * 4 + rg) * 264 + h * 64 + d] = f2bf(yv[0][n][rg]);
            }
            __syncthreads();
        }

        // out-proj (256->256) + bias + pad-mask -> outs; LN + residual -> hs
        {
            fx4 ac[2][2];
            #pragma unroll
            for (int m = 0; m < 2; ++m) { ac[m][0] = (fx4){0.f,0.f,0.f,0.f}; ac[m][1] = (fx4){0.f,0.f,0.f,0.f}; }
            mfma_gemm<2, 2, 8>(ys_b, 264, 0, wo, 256, w * 2, ac, lane);
            __syncthreads();   // ys_b/v_cm dead; outs aliases them
            #pragma unroll
            for (int n = 0; n < 2; ++n) {
                int c = (w * 2 + n) * 16 + lo;
                float bias = obv[l * 256 + c];
                #pragma unroll
                for (int m = 0; m < 2; ++m)
                    #pragma unroll
                    for (int rg = 0; rg < 4; ++rg) {
                        int r = m * 16 + kg * 4 + rg;
                        outs[r * 257 + c] = (ac[m][n][rg] + bias) * padc[r];
                    }
            }
            __syncthreads();
            ln_update(outs, hs, hs_b, las + l * 256, lab + l * 256, true, w, lane);
            __syncthreads();
        }

        // mlp up (256->512) + ReLU -> us_b
        {
            fx4 au[2][4];
            #pragma unroll
            for (int m = 0; m < 2; ++m)
                #pragma unroll
                for (int n = 0; n < 4; ++n) au[m][n] = (fx4){0.f, 0.f, 0.f, 0.f};
            mfma_gemm<2, 4, 8>(hs_b, 264, 0, wu, 256, w * 4, au, lane);
            #pragma unroll
            for (int n = 0; n < 4; ++n) {
                int c = (w * 4 + n) * 16 + lo;
                #pragma unroll
                for (int m = 0; m < 2; ++m)
                    #pragma unroll
                    for (int rg = 0; rg < 4; ++rg)
                        us_b[(m * 16 + kg * 4 + rg) * 520 + c] = f2bf(fmaxf(au[m][n][rg], 0.f));
            }
            __syncthreads();
        }

        // mlp down (512->256) -> outs; LN + residual -> hs
        {
            fx4 ad[2][2];
            #pragma unroll
            for (int m = 0; m < 2; ++m) { ad[m][0] = (fx4){0.f,0.f,0.f,0.f}; ad[m][1] = (fx4){0.f,0.f,0.f,0.f}; }
            mfma_gemm<2, 2, 16>(us_b, 520, 0, wd, 512, w * 2, ad, lane);
            #pragma unroll
            for (int n = 0; n < 2; ++n) {
                int c = (w * 2 + n) * 16 + lo;
                #pragma unroll
                for (int m = 0; m < 2; ++m)
                    #pragma unroll
                    for (int rg = 0; rg < 4; ++rg)
                        outs[(m * 16 + kg * 4 + rg) * 257 + c] = ad[m][n][rg];
            }
            __syncthreads();
            ln_update(outs, hs, hs_b, lms + l * 256, lmb + l * 256, true, w, lane);
            __syncthreads();
        }
    }

    // ---- head (256->18) ----
    for (int idx = t; idx < 576; idx += 512) {
        int r = idx / 18, a = idx - r * 18;
        float acch = hb[a];
        #pragma unroll 8
        for (int k = 0; k < 256; ++k) acch = fmaf(hs[r * 256 + k], hw[k * 18 + a], acch);
        out[((size_t)b * 32 + r) * 18 + a] = acch;
    }
}

extern "C" void kernel_launch(void* const* d_in, const int* in_sizes, int n_in,
                              void* d_out, int out_size, void* d_ws, size_t ws_size,
                              hipStream_t stream)
{
    (void)in_sizes; (void)n_in; (void)out_size; (void)ws_size;
    const float* x   = (const float*)d_in[0];
    const unsigned char* pad = (const unsigned char*)d_in[1];
    const float* c0w = (const float*)d_in[2];
    const float* c0b = (const float*)d_in[3];
    const float* l0s = (const float*)d_in[4];
    const float* l0b = (const float*)d_in[5];
    const float* c1w = (const float*)d_in[6];
    const float* c1b = (const float*)d_in[7];
    const float* l1s = (const float*)d_in[8];
    const float* l1b = (const float*)d_in[9];
    const float* pw  = (const float*)d_in[10];
    const float* pb  = (const float*)d_in[11];
    const float* lps = (const float*)d_in[12];
    const float* lpb = (const float*)d_in[13];
    const float* qkvw = (const float*)d_in[14];
    const float* qkvb = (const float*)d_in[15];
    const float* ow  = (const float*)d_in[16];
    const float* obv = (const float*)d_in[17];
    const float* las = (const float*)d_in[18];
    const float* lab = (const float*)d_in[19];
    const float* upw = (const float*)d_in[20];
    const float* dww = (const float*)d_in[21];
    const float* lms = (const float*)d_in[22];
    const float* lmb = (const float*)d_in[23];
    const float* hw  = (const float*)d_in[24];
    const float* hb  = (const float*)d_in[25];
    float* out = (float*)d_out;

    char* ws = (char*)d_ws;
    size_t off = 0;
    auto alloc = [&](size_t bytes) -> void* {
        void* p = ws + off;
        off = (off + bytes + 255) & ~(size_t)255;
        return p;
    };
    unsigned short* wtb = (unsigned short*)alloc(20480 * 2);
    unsigned short* wpk = (unsigned short*)alloc((size_t)1064960 * 2);
    float* pooled = (float*)alloc(512 * 64 * 4);
    float* padf   = (float*)alloc(512 * 4);

    hipMemsetAsync(pooled, 0, 512 * 64 * 4, stream);
    k_pad<<<1, 512, 0, stream>>>(pad, padf);
    k_wprep<<<80, 256, 0, stream>>>(c1w, c0w, wtb);
    k_wpack<<<4160, 256, 0, stream>>>(qkvw, ow, upw, dww, pw, wpk);
    k_conv1<<<14336, 256, 0, stream>>>(x, wtb, c0b, l0s, l0b, c1b, l1s, l1b, pooled);
    k_xformer<<<16, 512, 0, stream>>>(pooled, padf, wpk, pb, lps, lpb,
                                      qkvb, obv, las, lab, lms, lmb, hw, hb, out);
}

// Round 7
// 406.994 us; speedup vs baseline: 2.4297x; 1.0711x over previous
//
#include <hip/hip_runtime.h>
#include <hip/hip_bf16.h>

#define LN_EPS 1e-6f

typedef __attribute__((ext_vector_type(8))) short bf16x8;
typedef __attribute__((ext_vector_type(4))) float fx4;

struct U8 { union { bf16x8 v; uint2 p[2]; }; };

__device__ __forceinline__ unsigned short f2bf(float f) {
    union { __hip_bfloat16 b; unsigned short u; } cv;
    cv.b = __float2bfloat16(f);
    return cv.u;
}

// ---------- pad dtype detector: u8 bool vs int32 ----------
__global__ void k_pad(const unsigned char* __restrict__ p, float* __restrict__ padf) {
    __shared__ int cnt;
    int t = threadIdx.x;                  // 512 threads
    if (t == 0) cnt = 0;
    __syncthreads();
    if (p[t]) atomicAdd(&cnt, 1);
    __syncthreads();
    float v;
    if (cnt > 256) v = p[t] ? 1.f : 0.f;                       // u8 bools
    else           v = ((const int*)p)[t] ? 1.f : 0.f;          // int32 per elem
    padf[t] = v;
}

// ---------- weight repack ----------
// wtb[0..18432): conv1 (3,3,32,64) -> [tap][co][kg][j] bf16
// wtb[18432..20480): conv0 (3,3,4,32) -> wc0[ch 32][k 64] bf16, k=(tap<<2)|ci, zero-padded k>=36
__global__ void k_wprep(const float* __restrict__ w1, const float* __restrict__ w0,
                        unsigned short* __restrict__ wtb) {
    int idx = blockIdx.x * 256 + threadIdx.x;   // 20480 exactly
    if (idx < 18432) {
        int j  = idx & 7;
        int kg = (idx >> 3) & 3;
        int co = (idx >> 5) & 63;
        int tp = idx >> 11;
        wtb[idx] = f2bf(w1[((size_t)tp * 32 + kg * 8 + j) * 64 + co]);
    } else {
        int r = idx - 18432;
        int ch = r >> 6, k = r & 63;
        float v = 0.f;
        if (k < 36) v = w0[(size_t)k * 32 + ch];   // (tap*4+ci)*32+ch == k*32+ch
        wtb[idx] = f2bf(v);
    }
}

// ---------- tail weight pack: all transformer weights -> bf16 col-major [N][K] ----------
// layout (elems): qkv 2*768*256 | out 2*256*256 | up 2*512*256 | down 2*256*512 | proj 256*64 | head 32*256
__global__ void k_wpack(const float* __restrict__ qkvw, const float* __restrict__ ow,
                        const float* __restrict__ upw, const float* __restrict__ dww,
                        const float* __restrict__ pw, const float* __restrict__ hw,
                        unsigned short* __restrict__ wpk)
{
    int idx = blockIdx.x * 256 + threadIdx.x;
    if (idx >= 1073152) return;
    float v;
    if (idx < 393216) {
        int l = idx / 196608, rm = idx % 196608, n = rm >> 8, k = rm & 255;
        v = qkvw[((size_t)l * 256 + k) * 768 + n];
    } else if (idx < 524288) {
        int r = idx - 393216, l = r >> 16, rm = r & 65535, n = rm >> 8, k = rm & 255;
        v = ow[((size_t)l * 256 + k) * 256 + n];
    } else if (idx < 786432) {
        int r = idx - 524288, l = r >> 17, rm = r & 131071, n = rm >> 8, k = rm & 255;
        v = upw[((size_t)l * 256 + k) * 512 + n];
    } else if (idx < 1048576) {
        int r = idx - 786432, l = r >> 17, rm = r & 131071, n = rm >> 9, k = rm & 511;
        v = dww[((size_t)l * 512 + k) * 256 + n];
    } else if (idx < 1064960) {
        int r = idx - 1048576, n = r >> 6, k = r & 63;
        v = pw[k * 256 + n];
    } else {
        int r = idx - 1064960, n = r >> 8, k = r & 255;
        v = (n < 18) ? hw[(size_t)k * 18 + n] : 0.f;
    }
    wpk[idx] = f2bf(v);
}

// ---------- fused conv0+conv1 + LN + ReLU + mean-pool ----------
// Block: one image x 3 output rows.
// Phase 0: stage x rows y0-2..y0+4 as bf16 -> xs[7][86][4] (zero-padded halo).
// Phase 1 (swapped): conv0 = MFMA(A=wc0, B=pixels); lane owns pixel, 8ch; LN(32) via 4 shfl.
// Phase 2 (swapped): conv1 = MFMA(A=conv1 weights, B=pixels from At).
//   D: lane (lo,kg) holds pixel wv*64+n*16+lo, channels m*16+kg*4+rg.
// Phase 3: LN(64) per pixel = in-lane sum(16) + 4 shfl; pool via 4-step butterfly.
__global__ __launch_bounds__(256, 3) void k_conv1(
    const float* __restrict__ x, const unsigned short* __restrict__ wtb,
    const float* __restrict__ c0b, const float* __restrict__ l0s, const float* __restrict__ l0b,
    const float* __restrict__ bias, const float* __restrict__ lns, const float* __restrict__ lnb,
    float* __restrict__ pooled)
{
    __shared__ __align__(16) unsigned short At[4][5][86][8];   // 27520 B
    __shared__ __align__(16) unsigned short xs[7][86][4];      // 4816 B
    __shared__ __align__(16) float pool_w[4][64];
    const int tid = threadIdx.x;
    const int img = blockIdx.x / 28;
    const int rg  = blockIdx.x - img * 28;
    const int y0  = rg * 3;

    const int lane = tid & 63;
    const int wv = tid >> 6;
    const int lo = lane & 15;
    const int kg = lane >> 4;

    // ---- phase 0: stage x (7 rows, bf16, halo-padded) + zero At/xs halo cols ----
    if (tid >= 64 && tid < 104) {
        int z = tid - 64;
        int zk = z / 10, rem = z - zk * 10, zr = rem >> 1, side = rem & 1;
        *reinterpret_cast<uint4*>(&At[zk][zr][side ? 85 : 0][0]) = (uint4){0, 0, 0, 0};
    }
    if (tid >= 104 && tid < 118) {
        int z = tid - 104, row = z >> 1, side = z & 1;
        *reinterpret_cast<uint2*>(&xs[row][side ? 85 : 0][0]) = (uint2){0, 0};
    }
    for (int i = tid; i < 588; i += 256) {
        int row = i / 84, c = i - row * 84;
        int gy = y0 - 2 + row;
        float4 v = (float4){0.f, 0.f, 0.f, 0.f};
        if (gy >= 0 && gy < 84)
            v = *reinterpret_cast<const float4*>(x + ((size_t)img * 7056 + gy * 84 + c) * 4);
        unsigned l32 = (unsigned)f2bf(v.x) | ((unsigned)f2bf(v.y) << 16);
        unsigned h32 = (unsigned)f2bf(v.z) | ((unsigned)f2bf(v.w) << 16);
        *reinterpret_cast<uint2*>(&xs[row][c + 1][0]) = (uint2){l32, h32};
    }
    __syncthreads();

    // ---- phase 1: conv0 via MFMA (operand-swapped) -> At ----
    {
        const unsigned short* wc0 = wtb + 18432;
        bf16x8 W0[2], W1[2];
        #pragma unroll
        for (int m = 0; m < 2; ++m) {
            W0[m] = *reinterpret_cast<const bf16x8*>(wc0 + (m * 16 + lo) * 64 + kg * 8);
            W1[m] = *reinterpret_cast<const bf16x8*>(wc0 + (m * 16 + lo) * 64 + 32 + kg * 8);
        }
        float cb[2][4], sg[2][4], bg[2][4];
        #pragma unroll
        for (int m = 0; m < 2; ++m)
            #pragma unroll
            for (int r = 0; r < 4; ++r) {
                int c = m * 16 + kg * 4 + r;
                cb[m][r] = c0b[c]; sg[m][r] = l0s[c]; bg[m][r] = l0b[c];
            }
        const int t0 = 2 * kg, t1 = 2 * kg + 1;
        const int dy0 = t0 / 3, dx0 = t0 % 3, dy1 = t1 / 3, dx1 = t1 % 3;
        const unsigned short* xsb = &xs[0][0][0];

        for (int it = 0; it < 7; ++it) {
            int np = it * 4 + wv;
            if (np >= 27) break;
            int px = np * 16 + lo;
            int pxc = px < 420 ? px : 419;
            int r5 = pxc / 84, col = pxc - r5 * 84;
            U8 a0u, a1u;
            a0u.p[0] = *reinterpret_cast<const uint2*>(xsb + ((r5 + dy0) * 86 + col + dx0) * 4);
            a0u.p[1] = *reinterpret_cast<const uint2*>(xsb + ((r5 + dy1) * 86 + col + dx1) * 4);
            if (kg == 0)
                a1u.p[0] = *reinterpret_cast<const uint2*>(xsb + ((r5 + 2) * 86 + col + 2) * 4);
            else
                a1u.p[0] = (uint2){0, 0};
            a1u.p[1] = (uint2){0, 0};

            fx4 c2[2];
            c2[0] = (fx4){0.f, 0.f, 0.f, 0.f};
            c2[1] = (fx4){0.f, 0.f, 0.f, 0.f};
            c2[0] = __builtin_amdgcn_mfma_f32_16x16x32_bf16(W0[0], a0u.v, c2[0], 0, 0, 0);
            c2[0] = __builtin_amdgcn_mfma_f32_16x16x32_bf16(W1[0], a1u.v, c2[0], 0, 0, 0);
            c2[1] = __builtin_amdgcn_mfma_f32_16x16x32_bf16(W0[1], a0u.v, c2[1], 0, 0, 0);
            c2[1] = __builtin_amdgcn_mfma_f32_16x16x32_bf16(W1[1], a1u.v, c2[1], 0, 0, 0);

            float v[2][4], s = 0.f, q = 0.f;
            #pragma unroll
            for (int m = 0; m < 2; ++m)
                #pragma unroll
                for (int r = 0; r < 4; ++r) {
                    v[m][r] = c2[m][r] + cb[m][r];
                    s += v[m][r]; q += v[m][r] * v[m][r];
                }
            s += __shfl_xor(s, 16); q += __shfl_xor(q, 16);
            s += __shfl_xor(s, 32); q += __shfl_xor(q, 32);
            float mn = s * (1.f / 32.f);
            float inv = rsqrtf(q * (1.f / 32.f) - mn * mn + LN_EPS);

            if (px < 420) {
                int yA = y0 - 1 + r5;
                bool gv = (unsigned)yA < 84u;
                #pragma unroll
                for (int m = 0; m < 2; ++m) {
                    uint2 pk = (uint2){0, 0};
                    if (gv) {
                        unsigned short o0 = f2bf(fmaxf((v[m][0] - mn) * inv * sg[m][0] + bg[m][0], 0.f));
                        unsigned short o1 = f2bf(fmaxf((v[m][1] - mn) * inv * sg[m][1] + bg[m][1], 0.f));
                        unsigned short o2 = f2bf(fmaxf((v[m][2] - mn) * inv * sg[m][2] + bg[m][2], 0.f));
                        unsigned short o3 = f2bf(fmaxf((v[m][3] - mn) * inv * sg[m][3] + bg[m][3], 0.f));
                        pk.x = (unsigned)o0 | ((unsigned)o1 << 16);
                        pk.y = (unsigned)o2 | ((unsigned)o3 << 16);
                    }
                    *reinterpret_cast<uint2*>(&At[2 * m + (kg >> 1)][r5][col + 1][(kg & 1) * 4]) = pk;
                }
            }
        }
    }
    __syncthreads();

    // ---- phase 2: conv1 implicit GEMM (operand-swapped: A=weights, B=pixels) ----
    int abase[4];
    #pragma unroll
    for (int n = 0; n < 4; ++n) {
        int pl = wv * 64 + n * 16 + lo;
        if (pl > 251) pl = 251;
        int rl = pl / 84;
        int c = pl - rl * 84;
        abase[n] = ((kg * 5 + rl) * 86 + c) * 8;
    }

    fx4 acc[4][4];   // acc[m][n]: D row-tile m (channels), col-tile n (pixels)
    #pragma unroll
    for (int m = 0; m < 4; ++m)
        #pragma unroll
        for (int n = 0; n < 4; ++n) acc[m][n] = (fx4){0.f, 0.f, 0.f, 0.f};

    const unsigned short* Abase = &At[0][0][0][0];
    #pragma unroll
    for (int dy = 0; dy < 3; ++dy) {
        #pragma unroll
        for (int dx = 0; dx < 3; ++dx) {
            const int t = dy * 3 + dx;
            bf16x8 Wf[4];
            #pragma unroll
            for (int m = 0; m < 4; ++m)
                Wf[m] = *reinterpret_cast<const bf16x8*>(
                    wtb + (size_t)((t * 64 + m * 16 + lo) * 4 + kg) * 8);
            #pragma unroll
            for (int n = 0; n < 4; ++n) {
                bf16x8 Pf = *reinterpret_cast<const bf16x8*>(Abase + abase[n] + (dy * 86 + dx) * 8);
                #pragma unroll
                for (int m = 0; m < 4; ++m)
                    acc[m][n] = __builtin_amdgcn_mfma_f32_16x16x32_bf16(Wf[m], Pf, acc[m][n], 0, 0, 0);
            }
        }
    }

    // ---- phase 3: bias + LN(64) + ReLU + pool (channel-in-lane layout) ----
    // pass 1: bias + per-pixel stats (in-lane 16 + shfl 16/32)
    float s4[4] = {0.f, 0.f, 0.f, 0.f}, q4[4] = {0.f, 0.f, 0.f, 0.f};
    #pragma unroll
    for (int m = 0; m < 4; ++m) {
        float4 cbv = *reinterpret_cast<const float4*>(bias + m * 16 + kg * 4);
        #pragma unroll
        for (int n = 0; n < 4; ++n)
            #pragma unroll
            for (int r = 0; r < 4; ++r) {
                float val = acc[m][n][r] + (&cbv.x)[r];
                acc[m][n][r] = val;
                s4[n] += val; q4[n] += val * val;
            }
    }
    float mn4[4], iv4[4], pval[4];
    #pragma unroll
    for (int n = 0; n < 4; ++n) {
        float s = s4[n], q = q4[n];
        s += __shfl_xor(s, 16); q += __shfl_xor(q, 16);
        s += __shfl_xor(s, 32); q += __shfl_xor(q, 32);
        float mn = s * (1.f / 64.f);
        mn4[n] = mn;
        iv4[n] = rsqrtf(q * (1.f / 64.f) - mn * mn + LN_EPS);
        pval[n] = (wv * 64 + n * 16 + lo < 252) ? 1.f : 0.f;
    }
    // pass 2: normalize + ReLU + pool accumulate
    float pool[4][4] = {{0.f}};
    #pragma unroll
    for (int m = 0; m < 4; ++m) {
        float4 sgv = *reinterpret_cast<const float4*>(lns + m * 16 + kg * 4);
        float4 bgv = *reinterpret_cast<const float4*>(lnb + m * 16 + kg * 4);
        #pragma unroll
        for (int n = 0; n < 4; ++n)
            #pragma unroll
            for (int r = 0; r < 4; ++r) {
                float o = fmaxf((acc[m][n][r] - mn4[n]) * iv4[n] * (&sgv.x)[r] + (&bgv.x)[r], 0.f);
                pool[m][r] = fmaf(o, pval[n], pool[m][r]);
            }
    }
    // butterfly over lo bits (offsets 1,2,4,8), then lane lo==0 of each kg writes 16 ch
    #pragma unroll
    for (int off = 1; off < 16; off <<= 1)
        #pragma unroll
        for (int m = 0; m < 4; ++m)
            #pragma unroll
            for (int r = 0; r < 4; ++r)
                pool[m][r] += __shfl_xor(pool[m][r], off);
    if (lo == 0) {
        #pragma unroll
        for (int m = 0; m < 4; ++m) {
            float4 pk = (float4){pool[m][0], pool[m][1], pool[m][2], pool[m][3]};
            *reinterpret_cast<float4*>(&pool_w[wv][m * 16 + kg * 4]) = pk;
        }
    }
    __syncthreads();
    if (tid < 64) {
        float s = pool_w[0][tid] + pool_w[1][tid] + pool_w[2][tid] + pool_w[3][tid];
        atomicAdd(&pooled[img * 64 + tid], s);
    }
}

// ================= fused per-batch transformer =================
template<int MT, int NT, int KS>
__device__ __forceinline__ void mfma_gemm(
    const unsigned short* A, int lda, int m0,
    const unsigned short* B, int ldb, int nt0,
    fx4 (&acc)[MT][NT], int lane)
{
    const int lo = lane & 15, kg = lane >> 4;
    #pragma unroll
    for (int ks = 0; ks < KS; ++ks) {
        const int k = ks * 32 + kg * 8;
        bf16x8 af[MT];
        #pragma unroll
        for (int m = 0; m < MT; ++m)
            af[m] = *reinterpret_cast<const bf16x8*>(A + (size_t)((m0 + m) * 16 + lo) * lda + k);
        #pragma unroll
        for (int n = 0; n < NT; ++n) {
            bf16x8 bf = *reinterpret_cast<const bf16x8*>(B + (size_t)((nt0 + n) * 16 + lo) * ldb + k);
            #pragma unroll
            for (int m = 0; m < MT; ++m)
                acc[m][n] = __builtin_amdgcn_mfma_f32_16x16x32_bf16(af[m], bf, acc[m][n], 0, 0, 0);
        }
    }
}

__device__ __forceinline__ void ln_update(
    const float* outs /*[32][257] LDS*/, float* hs, unsigned short* hs_b,
    const float* gs, const float* gb, bool resid, int w, int lane)
{
    #pragma unroll
    for (int i = 0; i < 4; ++i) {
        int r = w * 4 + i;
        float x[4], s = 0.f, q = 0.f;
        #pragma unroll
        for (int j = 0; j < 4; ++j) {
            x[j] = outs[r * 257 + lane + 64 * j];
            s += x[j]; q += x[j] * x[j];
        }
        #pragma unroll
        for (int off = 1; off < 64; off <<= 1) {
            s += __shfl_xor(s, off);
            q += __shfl_xor(q, off);
        }
        float mn = s * (1.f / 256.f);
        float inv = rsqrtf(q * (1.f / 256.f) - mn * mn + LN_EPS);
        #pragma unroll
        for (int j = 0; j < 4; ++j) {
            int c = lane + 64 * j;
            float nv = (x[j] - mn) * inv * gs[c] + gb[c];
            if (resid) nv += hs[r * 256 + c];
            hs[r * 256 + c] = nv;
            hs_b[r * 264 + c] = f2bf(nv);
        }
    }
}

__global__ __launch_bounds__(512) void k_xformer(
    const float* __restrict__ pooled, const float* __restrict__ padf,
    const unsigned short* __restrict__ wpk,
    const float* __restrict__ pb, const float* __restrict__ lps, const float* __restrict__ lpb,
    const float* __restrict__ qkvb, const float* __restrict__ obv,
    const float* __restrict__ las, const float* __restrict__ lab,
    const float* __restrict__ lms, const float* __restrict__ lmb,
    const float* __restrict__ hb, float* __restrict__ out)
{
    __shared__ __align__(16) char smem[124032];
    float* hs = (float*)(smem);
    unsigned short* hs_b = (unsigned short*)(smem + 32768);
    unsigned short* R1 = (unsigned short*)(smem + 49664);
    unsigned short* q_s = R1;                   // per-head stride 2304 elems
    unsigned short* k_s = R1 + 9216;
    unsigned short* us_b = R1;                  // [32][520]
    unsigned short* v_cm = (unsigned short*)(smem + 86528);    // [4][64][40], head stride 2560
    unsigned short* ys_b = (unsigned short*)(smem + 107008);   // [32][264]
    float* outs = (float*)(smem + 86528);       // [32][257]
    unsigned short* pool_b = (unsigned short*)(smem + 86528);  // [32][72]
    float* padc = (float*)(smem + 123904);

    const int b = blockIdx.x, t = threadIdx.x;
    const int w = t >> 6, lane = t & 63, lo = lane & 15, kg = lane >> 4;

    // ---- P0: load pad flags + pooled (mean) ----
    if (t < 32) padc[t] = padf[b * 32 + t];
    for (int i = t; i < 2048; i += 512) {
        int r = i >> 6, k = i & 63;
        pool_b[r * 72 + k] = f2bf(pooled[((size_t)b * 32 + r) * 64 + k] * (1.f / 7056.f));
    }
    __syncthreads();

    // ---- P1: proj (64->256) + bias + LN -> hs ----
    {
        fx4 acc[1][4];
        #pragma unroll
        for (int n = 0; n < 4; ++n) acc[0][n] = (fx4){0.f, 0.f, 0.f, 0.f};
        int m0 = w & 1, nt0 = (w >> 1) * 4;
        mfma_gemm<1, 4, 2>(pool_b, 72, m0, wpk + 1048576, 64, nt0, acc, lane);
        __syncthreads();   // pool_b dead; outs aliases it
        #pragma unroll
        for (int n = 0; n < 4; ++n) {
            int c = (nt0 + n) * 16 + lo;
            float bias = pb[c];
            #pragma unroll
            for (int rg = 0; rg < 4; ++rg)
                outs[(m0 * 16 + kg * 4 + rg) * 257 + c] = acc[0][n][rg] + bias;
        }
        __syncthreads();
        ln_update(outs, hs, hs_b, lps, lpb, false, w, lane);
        __syncthreads();
    }

    // ---- transformer layers ----
    for (int l = 0; l < 2; ++l) {
        const unsigned short* wq = wpk + (size_t)l * 196608;
        const unsigned short* wo = wpk + 393216 + (size_t)l * 65536;
        const unsigned short* wu = wpk + 524288 + (size_t)l * 131072;
        const unsigned short* wd = wpk + 786432 + (size_t)l * 131072;

        // qkv (256 -> 768) + bias + RoPE -> q_s, k_s, v_cm
        {
            fx4 acc[2][6];
            #pragma unroll
            for (int m = 0; m < 2; ++m)
                #pragma unroll
                for (int n = 0; n < 6; ++n) acc[m][n] = (fx4){0.f, 0.f, 0.f, 0.f};
            int nt0 = w * 6;
            mfma_gemm<2, 6, 8>(hs_b, 264, 0, wq, 256, nt0, acc, lane);
            #pragma unroll
            for (int n = 0; n < 6; ++n) {
                int c = (nt0 + n) * 16 + lo;
                int kind = c >> 8, cl = c & 255, h = cl >> 6, d = cl & 63;
                float bias = qkvb[l * 768 + c];
                if (kind < 2) {
                    int j = d >> 1;
                    float freq = exp2f(-(float)j * 0.41524101186f);
                    unsigned short* dst = (kind ? k_s : q_s) + h * 2304;
                    #pragma unroll
                    for (int m = 0; m < 2; ++m)
                        #pragma unroll
                        for (int rg = 0; rg < 4; ++rg) {
                            float val = acc[m][n][rg] + bias;
                            float prt = __shfl_xor(val, 1);
                            int r = m * 16 + kg * 4 + rg;
                            float sn, cs;
                            __sincosf((float)r * freq, &sn, &cs);
                            float rv = (d & 1) ? (val * cs + prt * sn) : (val * cs - prt * sn);
                            dst[r * 72 + d] = f2bf(rv);
                        }
                } else {
                    #pragma unroll
                    for (int m = 0; m < 2; ++m)
                        #pragma unroll
                        for (int rg = 0; rg < 4; ++rg) {
                            int r = m * 16 + kg * 4 + rg;
                            v_cm[(h * 64 + d) * 40 + r] = f2bf(acc[m][n][rg] + bias);
                        }
                }
            }
            __syncthreads();
        }

        // scores = QK^T * scale, mask, softmax -> pa (aliases q_s)
        {
            int h = w >> 1, mt = w & 1;
            fx4 sc[1][2];
            sc[0][0] = (fx4){0.f, 0.f, 0.f, 0.f};
            sc[0][1] = (fx4){0.f, 0.f, 0.f, 0.f};
            mfma_gemm<1, 2, 2>(q_s + h * 2304, 72, mt, k_s + h * 2304, 72, 0, sc, lane);
            __syncthreads();    // all q_s reads done before pa overwrites
            unsigned short* pa = R1 + h * 2304;   // [32][40]
            float pad0 = padc[lo], pad1 = padc[16 + lo];
            #pragma unroll
            for (int rg = 0; rg < 4; ++rg) {
                int qr = mt * 16 + kg * 4 + rg;
                float v0 = (lo <= qr && pad0 != 0.f) ? sc[0][0][rg] * 0.125f : -1e9f;
                float v1 = ((16 + lo) <= qr && pad1 != 0.f) ? sc[0][1][rg] * 0.125f : -1e9f;
                float mx = fmaxf(v0, v1);
                #pragma unroll
                for (int off = 1; off < 16; off <<= 1) mx = fmaxf(mx, __shfl_xor(mx, off));
                float e0 = __expf(v0 - mx), e1 = __expf(v1 - mx);
                float sm = e0 + e1;
                #pragma unroll
                for (int off = 1; off < 16; off <<= 1) sm += __shfl_xor(sm, off);
                float inv = 1.f / sm;
                pa[qr * 40 + lo] = f2bf(e0 * inv);
                pa[qr * 40 + 16 + lo] = f2bf(e1 * inv);
            }
            __syncthreads();
        }

        // y = P @ V -> ys_b
        {
            int h = w >> 1, mt = w & 1;
            fx4 yv[1][4];
            #pragma unroll
            for (int n = 0; n < 4; ++n) yv[0][n] = (fx4){0.f, 0.f, 0.f, 0.f};
            mfma_gemm<1, 4, 1>(R1 + h * 2304, 40, mt, v_cm + h * 2560, 40, 0, yv, lane);
            #pragma unroll
            for (int n = 0; n < 4; ++n) {
                int d = n * 16 + lo;
                #pragma unroll
                for (int rg = 0; rg < 4; ++rg)
                    ys_b[(mt * 16 + kg * 4 + rg) * 264 + h * 64 + d] = f2bf(yv[0][n][rg]);
            }
            __syncthreads();
        }

        // out-proj (256->256) + bias + pad-mask -> outs; LN + residual -> hs
        {
            fx4 ac[2][2];
            #pragma unroll
            for (int m = 0; m < 2; ++m) { ac[m][0] = (fx4){0.f,0.f,0.f,0.f}; ac[m][1] = (fx4){0.f,0.f,0.f,0.f}; }
            mfma_gemm<2, 2, 8>(ys_b, 264, 0, wo, 256, w * 2, ac, lane);
            __syncthreads();   // ys_b/v_cm dead; outs aliases them
            #pragma unroll
            for (int n = 0; n < 2; ++n) {
                int c = (w * 2 + n) * 16 + lo;
                float bias = obv[l * 256 + c];
                #pragma unroll
                for (int m = 0; m < 2; ++m)
                    #pragma unroll
                    for (int rg = 0; rg < 4; ++rg) {
                        int r = m * 16 + kg * 4 + rg;
                        outs[r * 257 + c] = (ac[m][n][rg] + bias) * padc[r];
                    }
            }
            __syncthreads();
            ln_update(outs, hs, hs_b, las + l * 256, lab + l * 256, true, w, lane);
            __syncthreads();
        }

        // mlp up (256->512) + ReLU -> us_b
        {
            fx4 au[2][4];
            #pragma unroll
            for (int m = 0; m < 2; ++m)
                #pragma unroll
                for (int n = 0; n < 4; ++n) au[m][n] = (fx4){0.f, 0.f, 0.f, 0.f};
            mfma_gemm<2, 4, 8>(hs_b, 264, 0, wu, 256, w * 4, au, lane);
            #pragma unroll
            for (int n = 0; n < 4; ++n) {
                int c = (w * 4 + n) * 16 + lo;
                #pragma unroll
                for (int m = 0; m < 2; ++m)
                    #pragma unroll
                    for (int rg = 0; rg < 4; ++rg)
                        us_b[(m * 16 + kg * 4 + rg) * 520 + c] = f2bf(fmaxf(au[m][n][rg], 0.f));
            }
            __syncthreads();
        }

        // mlp down (512->256) -> outs; LN + residual -> hs
        {
            fx4 ad[2][2];
            #pragma unroll
            for (int m = 0; m < 2; ++m) { ad[m][0] = (fx4){0.f,0.f,0.f,0.f}; ad[m][1] = (fx4){0.f,0.f,0.f,0.f}; }
            mfma_gemm<2, 2, 16>(us_b, 520, 0, wd, 512, w * 2, ad, lane);
            #pragma unroll
            for (int n = 0; n < 2; ++n) {
                int c = (w * 2 + n) * 16 + lo;
                #pragma unroll
                for (int m = 0; m < 2; ++m)
                    #pragma unroll
                    for (int rg = 0; rg < 4; ++rg)
                        outs[(m * 16 + kg * 4 + rg) * 257 + c] = ad[m][n][rg];
            }
            __syncthreads();
            ln_update(outs, hs, hs_b, lms + l * 256, lmb + l * 256, true, w, lane);
            __syncthreads();
        }
    }

    // ---- head (256->18) via MFMA (hwb bf16 [32][256] at wpk+1064960, n>=18 zero) ----
    if (w < 4) {
        int mt = w >> 1, nt = w & 1;
        fx4 hd[1][1];
        hd[0][0] = (fx4){0.f, 0.f, 0.f, 0.f};
        mfma_gemm<1, 1, 8>(hs_b, 264, mt, wpk + 1064960, 256, nt, hd, lane);
        int cc = nt * 16 + lo;
        if (cc < 18) {
            float bias = hb[cc];
            #pragma unroll
            for (int rg = 0; rg < 4; ++rg)
                out[((size_t)b * 32 + mt * 16 + kg * 4 + rg) * 18 + cc] = hd[0][0][rg] + bias;
        }
    }
}

extern "C" void kernel_launch(void* const* d_in, const int* in_sizes, int n_in,
                              void* d_out, int out_size, void* d_ws, size_t ws_size,
                              hipStream_t stream)
{
    (void)in_sizes; (void)n_in; (void)out_size; (void)ws_size;
    const float* x   = (const float*)d_in[0];
    const unsigned char* pad = (const unsigned char*)d_in[1];
    const float* c0w = (const float*)d_in[2];
    const float* c0b = (const float*)d_in[3];
    const float* l0s = (const float*)d_in[4];
    const float* l0b = (const float*)d_in[5];
    const float* c1w = (const float*)d_in[6];
    const float* c1b = (const float*)d_in[7];
    const float* l1s = (const float*)d_in[8];
    const float* l1b = (const float*)d_in[9];
    const float* pw  = (const float*)d_in[10];
    const float* pb  = (const float*)d_in[11];
    const float* lps = (const float*)d_in[12];
    const float* lpb = (const float*)d_in[13];
    const float* qkvw = (const float*)d_in[14];
    const float* qkvb = (const float*)d_in[15];
    const float* ow  = (const float*)d_in[16];
    const float* obv = (const float*)d_in[17];
    const float* las = (const float*)d_in[18];
    const float* lab = (const float*)d_in[19];
    const float* upw = (const float*)d_in[20];
    const float* dww = (const float*)d_in[21];
    const float* lms = (const float*)d_in[22];
    const float* lmb = (const float*)d_in[23];
    const float* hw  = (const float*)d_in[24];
    const float* hb  = (const float*)d_in[25];
    float* out = (float*)d_out;

    char* ws = (char*)d_ws;
    size_t off = 0;
    auto alloc = [&](size_t bytes) -> void* {
        void* p = ws + off;
        off = (off + bytes + 255) & ~(size_t)255;
        return p;
    };
    unsigned short* wtb = (unsigned short*)alloc(20480 * 2);
    unsigned short* wpk = (unsigned short*)alloc((size_t)1073152 * 2);
    float* pooled = (float*)alloc(512 * 64 * 4);
    float* padf   = (float*)alloc(512 * 4);

    hipMemsetAsync(pooled, 0, 512 * 64 * 4, stream);
    k_pad<<<1, 512, 0, stream>>>(pad, padf);
    k_wprep<<<80, 256, 0, stream>>>(c1w, c0w, wtb);
    k_wpack<<<4192, 256, 0, stream>>>(qkvw, ow, upw, dww, pw, hw, wpk);
    k_conv1<<<14336, 256, 0, stream>>>(x, wtb, c0b, l0s, l0b, c1b, l1s, l1b, pooled);
    k_xformer<<<16, 512, 0, stream>>>(pooled, padf, wpk, pb, lps, lpb,
                                      qkvb, obv, las, lab, lms, lmb, hb, out);
}